// Round 4
// baseline (1322.775 us; speedup 1.0000x reference)
//
#include <hip/hip_runtime.h>
#include <hip/hip_bf16.h>

typedef unsigned short u16;
typedef unsigned long long u64;
typedef float f32x2 __attribute__((ext_vector_type(2)));

#define NN 4096
#define SS 1024
#define NSAMP 32
#define NGRP 16384            // 16*1024 groups
#define ROWS 524288           // NGRP*NSAMP
#define BN_EPS_F 1e-5f
#define INV_ROWS (1.0f/524288.0f)

// ---------------- packed fp32 ops (VOP3P, full-rate fp32 path on CDNA) ----------------
// Each half rounds independently -> bitwise identical to scalar __fadd_rn/__fmul_rn/fmaf.
__device__ __forceinline__ f32x2 pk_add(f32x2 a, f32x2 b){
    f32x2 d; asm("v_pk_add_f32 %0, %1, %2" : "=v"(d) : "v"(a), "v"(b)); return d;
}
__device__ __forceinline__ f32x2 pk_mul(f32x2 a, f32x2 b){
    f32x2 d; asm("v_pk_mul_f32 %0, %1, %2" : "=v"(d) : "v"(a), "v"(b)); return d;
}
__device__ __forceinline__ f32x2 pk_fma(f32x2 a, f32x2 b, f32x2 c){
    f32x2 d; asm("v_pk_fma_f32 %0, %1, %2, %3" : "=v"(d) : "v"(a), "v"(b), "v"(c)); return d;
}

// ---------------- FPS v9: v7 4-wave structure + packed distance update ----------------
// v7 (256thr scalar) = 677us. R2 proved pk math is bitwise-exact (absmax unchanged) but
// 512thr barrier skew regressed; v9 keeps the 256thr/4-wave sync structure byte-for-byte
// and only packs the 16-pt distance update (64 pk ops vs 128 scalar: ~128 cyc/iter less
// wave-issue on the serial chain). Argmax key/tree/DPP/merge identical to v7: u64 total
// order is tree-order-invariant -> same winner bitwise.
#define FPS_DPP_STEP(CTRL)                                                              \
    {   int hs = __builtin_amdgcn_update_dpp((int)(bk >> 32), (int)(bk >> 32),          \
                                             CTRL, 0xf, 0xf, false);                    \
        int ls = __builtin_amdgcn_update_dpp((int)bk, (int)bk, CTRL, 0xf, 0xf, false);  \
        u64 o = ((u64)(unsigned int)hs << 32) | (unsigned int)ls;                       \
        bk = bk > o ? bk : o; }

__global__ __launch_bounds__(256, 1) void fps_kernel(const float* __restrict__ xyz,
                                                     float* __restrict__ out,
                                                     float* __restrict__ stats){
    __shared__ float xs[NN], ys[NN], zs[NN];
    __shared__ u64 red[2][4];
    const int b = blockIdx.x;
    const int tid = threadIdx.x;
    if (b == 0){ stats[tid] = 0.0f; stats[tid + 256] = 0.0f; }   // folded zero_kernel
    const float* xb = xyz + (size_t)b * NN * 3;
    f32x2 px2[8], py2[8], pz2[8], d2[8];
    unsigned int inv[16];
    #pragma unroll
    for (int q = 0; q < 8; ++q){
        int i0 = tid + (2*q)   * 256;
        int i1 = tid + (2*q+1) * 256;
        float x0 = xb[i0*3+0], y0 = xb[i0*3+1], z0 = xb[i0*3+2];
        float x1 = xb[i1*3+0], y1 = xb[i1*3+1], z1 = xb[i1*3+2];
        px2[q].x = x0; px2[q].y = x1;
        py2[q].x = y0; py2[q].y = y1;
        pz2[q].x = z0; pz2[q].y = z1;
        xs[i0] = x0; ys[i0] = y0; zs[i0] = z0;
        xs[i1] = x1; ys[i1] = y1; zs[i1] = z1;
        d2[q].x = 1e10f; d2[q].y = 1e10f;          // ref init 1e10 (exact f32)
        inv[2*q]   = (unsigned int)(NN - 1 - i0);  // loop-invariant key low words
        inv[2*q+1] = (unsigned int)(NN - 1 - i1);
    }
    int cur = 0;
    __syncthreads();
    if (tid == 0){  // fps_idx[b,0] == 0 (scan emits carry before update)
        float* of = out + (size_t)b * SS * 3;
        of[0] = xs[0]; of[1] = ys[0]; of[2] = zs[0];
    }
    const int wave = tid >> 6, lane = tid & 63;
    for (int it = 1; it < SS; ++it){
        float cx = xs[cur], cy = ys[cur], cz = zs[cur];   // uniform LDS broadcast
        // a + (-c) is IEEE-identical to a - c; broadcast negated centroid once
        f32x2 ncx; ncx.x = -cx; ncx.y = -cx;
        f32x2 ncy; ncy.x = -cy; ncy.y = -cy;
        f32x2 ncz; ncz.x = -cz; ncz.y = -cz;
        u64 t[16];
        // strict fp32 order ((dx*dx+dy*dy)+dz*dz); pk halves round independently ->
        // bitwise identical to the scalar v7 sequence per point
        #pragma unroll
        for (int q = 0; q < 8; ++q){
            f32x2 dx = pk_add(px2[q], ncx);
            f32x2 dy = pk_add(py2[q], ncy);
            f32x2 dz = pk_add(pz2[q], ncz);
            f32x2 xx = pk_mul(dx, dx);
            f32x2 yy = pk_mul(dy, dy);
            f32x2 ss = pk_add(xx, yy);
            f32x2 zz = pk_mul(dz, dz);
            f32x2 dd = pk_add(ss, zz);
            d2[q].x = fminf(d2[q].x, dd.x);
            d2[q].y = fminf(d2[q].y, dd.y);
            t[2*q]   = ((u64)__float_as_uint(d2[q].x) << 32) | inv[2*q];
            t[2*q+1] = ((u64)__float_as_uint(d2[q].y) << 32) | inv[2*q+1];
        }
        // pairwise tree (ILP) instead of serial 16-deep chain
        #pragma unroll
        for (int s = 8; s >= 1; s >>= 1)
            #pragma unroll
            for (int i2 = 0; i2 < s; ++i2)
                if (t[i2 + s] > t[i2]) t[i2] = t[i2 + s];
        u64 bk = t[0];
        // DPP reduce over 64 lanes -> winner at lane 63 (VALU pipe, no DS latency)
        FPS_DPP_STEP(0x111)  // row_shr:1
        FPS_DPP_STEP(0x112)  // row_shr:2
        FPS_DPP_STEP(0x114)  // row_shr:4
        FPS_DPP_STEP(0x118)  // row_shr:8  -> lane15 of each row = row max
        FPS_DPP_STEP(0x142)  // row_bcast:15 -> lane31/63 accumulate halves
        FPS_DPP_STEP(0x143)  // row_bcast:31 -> lane63 = wave max
        unsigned int wh = (unsigned int)__builtin_amdgcn_readlane((int)(bk >> 32), 63);
        unsigned int wl = (unsigned int)__builtin_amdgcn_readlane((int)bk, 63);
        if (lane == 0) red[it & 1][wave] = ((u64)wh << 32) | wl;
        __syncthreads();                       // double-buffered red: one barrier/iter
        u64 m0 = red[it & 1][0];
        #pragma unroll
        for (int w = 1; w < 4; ++w){
            u64 o = red[it & 1][w];
            m0 = m0 > o ? m0 : o;
        }
        cur = (NN - 1 - (int)(m0 & 0xffffffffu)) & (NN - 1);
        if (tid == 0){
            float* of = out + ((size_t)b * SS + it) * 3;
            of[0] = xs[cur]; of[1] = ys[cur]; of[2] = zs[cur];
        }
    }
}

// ---------------- ball query v3: 512-pt super-chunks, pipelined masks ----------------
__global__ __launch_bounds__(256) void ballq_kernel(const float* __restrict__ xyz,
                                                    const float* __restrict__ outc,
                                                    u16* __restrict__ gidx){
    const int g = (blockIdx.x << 2) + (threadIdx.x >> 6);
    const int lane = threadIdx.x & 63;
    const int b = g >> 10;
    const float rr = 0.04f;   // np.float32 promotion of python 0.2*0.2
    const float* c = outc + (size_t)g * 3;
    float cx = c[0], cy = c[1], cz = c[2];
    float sa = __fadd_rn(__fadd_rn(__fmul_rn(cx,cx), __fmul_rn(cy,cy)), __fmul_rn(cz,cz));
    const float* xb = xyz + (size_t)b * NN * 3;
    u16* outp = gidx + (size_t)g * NSAMP;
    int count = 0, first = -1;
    const u64 below = (1ull << lane) - 1ull;
    for (int base = 0; base < NN && count < NSAMP; base += 512){
        u64 masks[8];
        #pragma unroll
        for (int u = 0; u < 8; ++u){          // 8 independent distance+ballot: loads pipeline
            int n = base + u * 64 + lane;
            float x = xb[n*3+0], y = xb[n*3+1], z = xb[n*3+2];
            float sb = __fadd_rn(__fadd_rn(__fmul_rn(x,x), __fmul_rn(y,y)), __fmul_rn(z,z));
            float dt = __fadd_rn(__fadd_rn(__fmul_rn(cx,x), __fmul_rn(cy,y)), __fmul_rn(cz,z));
            float sq = __fadd_rn(__fsub_rn(sa, __fmul_rn(2.0f, dt)), sb);
            masks[u] = __ballot(!(sq > rr));
        }
        #pragma unroll
        for (int u = 0; u < 8; ++u){          // append phase: VALU-only serial chain
            u64 m = masks[u];
            bool w = (m >> lane) & 1ull;
            int pos = __popcll(m & below);
            if (w && (count + pos) < NSAMP) outp[count + pos] = (u16)(base + u * 64 + lane);
            if (first < 0 && m != 0ull) first = base + u * 64 + (__ffsll((long long)m) - 1);
            count += __popcll(m);
        }
    }
    for (int j = count + lane; j < NSAMP; j += 64) outp[j] = (u16)first;
}

// ---------------- shared helpers ----------------
__device__ __forceinline__ void gather_row(const float* __restrict__ xyz, const float* __restrict__ pts,
                                           const float* __restrict__ outc, const u16* __restrict__ gidx,
                                           int row, float* x){
    int g = row >> 5;
    int b = row >> 15;
    int i = gidx[row];
    const float* cc = outc + (size_t)g * 3;
    const float* xp = xyz + ((size_t)b * NN + i) * 3;
    const float* pp = pts + ((size_t)b * NN + i) * 6;
    x[0] = __fsub_rn(xp[0], cc[0]);
    x[1] = __fsub_rn(xp[1], cc[1]);
    x[2] = __fsub_rn(xp[2], cc[2]);
    #pragma unroll
    for (int k = 0; k < 6; ++k) x[3+k] = pp[k];
}

__device__ __forceinline__ void bn_coef(const float* sums, const float* ssqs,
                                        const float* g, const float* bbv, int ch,
                                        float* sc, float* sh){
    float mu = sums[ch] * INV_ROWS;
    float var = fmaf(-mu, mu, ssqs[ch] * INV_ROWS);
    var = fmaxf(var, 0.0f);
    float is = rsqrtf(var + BN_EPS_F);
    float s = is * g[ch];
    sc[ch] = s;
    sh[ch] = fmaf(-mu, s, bbv[ch]);
}

// ---------------- stats1 v2: one row/thread + LDS-transpose reduce ----------------
__global__ __launch_bounds__(256, 1) void stats1_kernel(const float* __restrict__ xyz, const float* __restrict__ pts,
                                                        const float* __restrict__ outc, const u16* __restrict__ gidx,
                                                        const float* __restrict__ W0f, const float* __restrict__ b0f,
                                                        float* __restrict__ stats){
    __shared__ float tr[256 * 65];
    __shared__ float accs[4][64], accq[4][64];
    const int row = blockIdx.x * 256 + threadIdx.x;
    float x[9];
    gather_row(xyz, pts, outc, gidx, row, x);
    #pragma unroll
    for (int j = 0; j < 64; ++j){
        float acc = b0f[j];
        #pragma unroll
        for (int k = 0; k < 9; ++k) acc = fmaf(x[k], W0f[j*9+k], acc);
        tr[threadIdx.x * 65 + j] = acc;
    }
    __syncthreads();
    const int ch = threadIdx.x & 63, qq = threadIdx.x >> 6;
    float s = 0.f, q = 0.f;
    for (int r = 0; r < 64; ++r){
        float v = tr[(qq * 64 + r) * 65 + ch];
        s += v; q = fmaf(v, v, q);
    }
    accs[qq][ch] = s; accq[qq][ch] = q;
    __syncthreads();
    if (threadIdx.x < 64){
        int c = threadIdx.x;
        atomicAdd(&stats[c], (accs[0][c] + accs[1][c]) + (accs[2][c] + accs[3][c]));
    } else if (threadIdx.x < 128){
        int c = threadIdx.x - 64;
        atomicAdd(&stats[64 + c], (accq[0][c] + accq[1][c]) + (accq[2][c] + accq[3][c]));
    }
}

// ---------------- stats2 v3: pk_fma W1 (bitwise-identical accumulation order) ----------------
__global__ __launch_bounds__(256, 1) void stats2_kernel(const float* __restrict__ xyz, const float* __restrict__ pts,
                                                        const float* __restrict__ outc, const u16* __restrict__ gidx,
                                                        const float* __restrict__ W0f, const float* __restrict__ b0f,
                                                        const float* __restrict__ W1f, const float* __restrict__ b1f,
                                                        const float* __restrict__ g0, const float* __restrict__ bb0,
                                                        float* __restrict__ stats){
    __shared__ float sc1[64], sh1[64];
    __shared__ float tr[256 * 65];
    __shared__ float accs[4][64], accq[4][64];
    if (threadIdx.x < 64) bn_coef(stats + 0, stats + 64, g0, bb0, threadIdx.x, sc1, sh1);
    __syncthreads();
    const int row = blockIdx.x * 256 + threadIdx.x;
    float x[9];
    gather_row(xyz, pts, outc, gidx, row, x);
    f32x2 x2p[32];
    #pragma unroll
    for (int j = 0; j < 64; ++j){
        float acc = b0f[j];
        #pragma unroll
        for (int k = 0; k < 9; ++k) acc = fmaf(x[k], W0f[j*9+k], acc);
        float v = fmaxf(fmaf(acc, sc1[j], sh1[j]), 0.f);
        if (j & 1) x2p[j >> 1].y = v; else x2p[j >> 1].x = v;
    }
    // W1: A={a0,a1}, B={a2,a3}; pk pairs (k,k+1)/(k+2,k+3), k+=4 -> same per-acc FMA
    // sequence and same (a0+a1)+(a2+a3) combine as the scalar version: bit-identical.
    for (int ch = 0; ch < 64; ++ch){
        const f32x2* wp = (const f32x2*)(W1f + ch * 64);
        f32x2 A; A.x = b1f[ch]; A.y = 0.f;
        f32x2 B; B.x = 0.f;     B.y = 0.f;
        #pragma unroll
        for (int k2 = 0; k2 < 32; k2 += 2){
            A = pk_fma(x2p[k2],     wp[k2],     A);
            B = pk_fma(x2p[k2 + 1], wp[k2 + 1], B);
        }
        tr[threadIdx.x * 65 + ch] = (A.x + A.y) + (B.x + B.y);
    }
    __syncthreads();
    const int ch = threadIdx.x & 63, qq = threadIdx.x >> 6;
    float s = 0.f, q = 0.f;
    for (int r = 0; r < 64; ++r){
        float v = tr[(qq * 64 + r) * 65 + ch];
        s += v; q = fmaf(v, v, q);
    }
    accs[qq][ch] = s; accq[qq][ch] = q;
    __syncthreads();
    if (threadIdx.x < 64){
        int c = threadIdx.x;
        atomicAdd(&stats[128 + c], (accs[0][c] + accs[1][c]) + (accs[2][c] + accs[3][c]));
    } else if (threadIdx.x < 128){
        int c = threadIdx.x - 64;
        atomicAdd(&stats[192 + c], (accq[0][c] + accq[1][c]) + (accq[2][c] + accq[3][c]));
    }
}

// ---------------- stats3 v3: LDS-staged x3 + pk_fma W1/W2 ----------------
__global__ __launch_bounds__(256, 1) void stats3_kernel(const float* __restrict__ xyz, const float* __restrict__ pts,
                                                        const float* __restrict__ outc, const u16* __restrict__ gidx,
                                                        const float* __restrict__ W0f, const float* __restrict__ b0f,
                                                        const float* __restrict__ W1f, const float* __restrict__ b1f,
                                                        const float* __restrict__ W2f, const float* __restrict__ b2f,
                                                        const float* __restrict__ g0, const float* __restrict__ bb0,
                                                        const float* __restrict__ g1, const float* __restrict__ bb1,
                                                        float* __restrict__ stats,
                                                        float* __restrict__ pmax, float* __restrict__ pmin){
    __shared__ float sc1[64], sh1[64], sc2[64], sh2[64];
    __shared__ float tr[256 * 65];
    __shared__ float accs[4][64], accq[4][64];
    if (threadIdx.x < 64){
        bn_coef(stats + 0,   stats + 64,  g0, bb0, threadIdx.x, sc1, sh1);
        bn_coef(stats + 128, stats + 192, g1, bb1, threadIdx.x, sc2, sh2);
    }
    __syncthreads();
    const int row = blockIdx.x * 256 + threadIdx.x;
    float x[9];
    gather_row(xyz, pts, outc, gidx, row, x);
    f32x2 x2p[32];
    #pragma unroll
    for (int j = 0; j < 64; ++j){
        float acc = b0f[j];
        #pragma unroll
        for (int k = 0; k < 9; ++k) acc = fmaf(x[k], W0f[j*9+k], acc);
        float v = fmaxf(fmaf(acc, sc1[j], sh1[j]), 0.f);
        if (j & 1) x2p[j >> 1].y = v; else x2p[j >> 1].x = v;
    }
    // phase B: x3[j] -> LDS (own row, same-thread RAW; kills x2/x3 dual-liveness spills)
    #pragma unroll
    for (int j = 0; j < 64; ++j){
        const f32x2* wp = (const f32x2*)(W1f + j * 64);
        f32x2 A; A.x = b1f[j]; A.y = 0.f;
        f32x2 B; B.x = 0.f;    B.y = 0.f;
        #pragma unroll
        for (int k2 = 0; k2 < 32; k2 += 2){
            A = pk_fma(x2p[k2],     wp[k2],     A);
            B = pk_fma(x2p[k2 + 1], wp[k2 + 1], B);
        }
        tr[threadIdx.x * 65 + j] = fmaxf(fmaf((A.x + A.y) + (B.x + B.y), sc2[j], sh2[j]), 0.f);
    }
    // compiler barrier: forbid store-to-load forwarding of the staged x3 (which
    // would resurrect the x2+x3 dual-liveness and the spills)
    asm volatile("" ::: "memory");
    f32x2 x3p[32];
    #pragma unroll
    for (int j = 0; j < 32; ++j){
        x3p[j].x = tr[threadIdx.x * 65 + 2*j];
        x3p[j].y = tr[threadIdx.x * 65 + 2*j + 1];
    }
    const int ch = threadIdx.x & 63, qq = threadIdx.x >> 6;
    for (int half = 0; half < 2; ++half){
        for (int c64 = 0; c64 < 64; ++c64){
            int c = half * 64 + c64;
            const f32x2* wp = (const f32x2*)(W2f + c * 64);
            f32x2 A; A.x = b2f[c]; A.y = 0.f;
            f32x2 B; B.x = 0.f;    B.y = 0.f;
            #pragma unroll
            for (int k2 = 0; k2 < 32; k2 += 2){
                A = pk_fma(x3p[k2],     wp[k2],     A);
                B = pk_fma(x3p[k2 + 1], wp[k2 + 1], B);
            }
            tr[threadIdx.x * 65 + c64] = (A.x + A.y) + (B.x + B.y);
        }
        __syncthreads();
        // quarter qq = rows [qq*64, qq*64+64) = groups 2qq (first 32 rows) and 2qq+1
        float s = 0.f, q = 0.f;
        float mxA = -1e30f, mnA = 1e30f, mxB = -1e30f, mnB = 1e30f;
        for (int r = 0; r < 32; ++r){
            float v = tr[(qq * 64 + r) * 65 + ch];
            s += v; q = fmaf(v, v, q);
            mxA = fmaxf(mxA, v); mnA = fminf(mnA, v);
        }
        for (int r = 32; r < 64; ++r){
            float v = tr[(qq * 64 + r) * 65 + ch];
            s += v; q = fmaf(v, v, q);
            mxB = fmaxf(mxB, v); mnB = fminf(mnB, v);
        }
        int c = half * 64 + ch;
        int gA = blockIdx.x * 8 + 2 * qq;
        pmax[(size_t)gA * 128 + c] = mxA;           // coalesced across lanes (c consecutive)
        pmin[(size_t)gA * 128 + c] = mnA;
        pmax[(size_t)(gA + 1) * 128 + c] = mxB;
        pmin[(size_t)(gA + 1) * 128 + c] = mnB;
        accs[qq][ch] = s; accq[qq][ch] = q;
        __syncthreads();
        if (threadIdx.x < 64){
            int cc = half * 64 + threadIdx.x;
            atomicAdd(&stats[256 + cc], (accs[0][threadIdx.x] + accs[1][threadIdx.x])
                                      + (accs[2][threadIdx.x] + accs[3][threadIdx.x]));
        } else if (threadIdx.x < 128){
            int t = threadIdx.x - 64;
            int cc = half * 64 + t;
            atomicAdd(&stats[384 + cc], (accq[0][t] + accq[1][t]) + (accq[2][t] + accq[3][t]));
        }
        __syncthreads();   // tr + accs reuse protection for next half
    }
}

// ---------------- BN3 applied to group max/min, relu, write out region 1 (f32) ----------------
__global__ __launch_bounds__(256) void pool_kernel(const float* __restrict__ stats,
                                                   const float* __restrict__ g2, const float* __restrict__ bb2,
                                                   const float* __restrict__ pmax, const float* __restrict__ pmin,
                                                   float* __restrict__ out){
    __shared__ float sc[128], sh[128];
    if (threadIdx.x < 128) bn_coef(stats + 256, stats + 384, g2, bb2, threadIdx.x, sc, sh);
    __syncthreads();
    int o = blockIdx.x * 256 + threadIdx.x;   // o = g*128 + ch, o < NGRP*128
    int ch = o & 127;
    float a = fmaf(pmax[o], sc[ch], sh[ch]);
    float b = fmaf(pmin[o], sc[ch], sh[ch]);  // affine maps interval endpoints (sc<0 covered)
    out[NGRP * 3 + o] = fmaxf(fmaxf(a, b), 0.0f);
}

extern "C" void kernel_launch(void* const* d_in, const int* in_sizes, int n_in,
                              void* d_out, int out_size, void* d_ws, size_t ws_size,
                              hipStream_t stream){
    const float* xyz = (const float*)d_in[0];
    const float* pts = (const float*)d_in[1];
    const float* W0  = (const float*)d_in[2];
    const float* b0  = (const float*)d_in[3];
    const float* g0  = (const float*)d_in[4];
    const float* bb0 = (const float*)d_in[5];
    const float* W1  = (const float*)d_in[6];
    const float* b1  = (const float*)d_in[7];
    const float* g1  = (const float*)d_in[8];
    const float* bb1 = (const float*)d_in[9];
    const float* W2  = (const float*)d_in[10];
    const float* b2  = (const float*)d_in[11];
    const float* g2  = (const float*)d_in[12];
    const float* bb2 = (const float*)d_in[13];
    float* out = (float*)d_out;   // f32 outputs: [new_xyz 49152 | new_points 2097152]

    // ws layout (bytes): stats[512f]@0 | gidx[524288 u16]@2048 |
    //                    pmax[2097152f]@1050624 | pmin@9439232 ; total 17,827,840
    if (ws_size < 17827840u) return;
    char*  ws    = (char*)d_ws;
    float* stats = (float*)ws;
    u16*   gidx  = (u16*)  (ws + 2048);
    float* pmax  = (float*)(ws + 1050624);
    float* pmin  = (float*)(ws + 9439232);

    fps_kernel  <<<16, 256, 0, stream>>>(xyz, out, stats);   // block 0 also zeroes stats
    ballq_kernel<<<NGRP/4, 256, 0, stream>>>(xyz, out, gidx);
    stats1_kernel<<<ROWS/256, 256, 0, stream>>>(xyz, pts, out, gidx, W0, b0, stats);
    stats2_kernel<<<ROWS/256, 256, 0, stream>>>(xyz, pts, out, gidx, W0, b0, W1, b1, g0, bb0, stats);
    stats3_kernel<<<ROWS/256, 256, 0, stream>>>(xyz, pts, out, gidx, W0, b0, W1, b1, W2, b2,
                                                g0, bb0, g1, bb1, stats, pmax, pmin);
    pool_kernel <<<NGRP*128/256, 256, 0, stream>>>(stats, g2, bb2, pmax, pmin, out);
}

// Round 5
// 1276.898 us; speedup vs baseline: 1.0359x; 1.0359x over previous
//
#include <hip/hip_runtime.h>

typedef unsigned short u16;
typedef unsigned long long u64;
typedef float f32x2 __attribute__((ext_vector_type(2)));

#define NN 4096
#define SS 1024
#define NSAMP 32
#define NGRP 16384            // 16*1024 groups
#define ROWS 524288           // NGRP*NSAMP
#define BN_EPS_F 1e-5f
#define INV_ROWS (1.0f/524288.0f)

// ---------------- packed fp32 FMA (VOP3P) -- throughput kernels only ----------------
// R3 proved: wins in multi-wave throughput kernels (stats2/3, -132us); R4 proved:
// LOSES on the single-wave latency chain (fps, +55us from operand marshaling).
__device__ __forceinline__ f32x2 pk_fma(f32x2 a, f32x2 b, f32x2 c){
    f32x2 d; asm("v_pk_fma_f32 %0, %1, %2, %3" : "=v"(d) : "v"(a), "v"(b), "v"(c)); return d;
}

// ---------------- FPS v10: v7 scalar structure (662us proven) + xyz4 packed LDS ----------------
// Key = (distbits<<32)|(NN-1-idx): exact argmax with first-index tie-break.
// Only delta vs v7: centroid broadcast is ONE ds_read_b128 from xyz4[] instead of 3
// ds_read_b32 from xs/ys/zs (saves ~2 issue+dep slots on the serial chain).
#define FPS_DPP_STEP(CTRL)                                                              \
    {   int hs = __builtin_amdgcn_update_dpp((int)(bk >> 32), (int)(bk >> 32),          \
                                             CTRL, 0xf, 0xf, false);                    \
        int ls = __builtin_amdgcn_update_dpp((int)bk, (int)bk, CTRL, 0xf, 0xf, false);  \
        u64 o = ((u64)(unsigned int)hs << 32) | (unsigned int)ls;                       \
        bk = bk > o ? bk : o; }

__global__ __launch_bounds__(256, 1) void fps_kernel(const float* __restrict__ xyz,
                                                     float* __restrict__ out,
                                                     float* __restrict__ stats){
    __shared__ float xyz4[NN * 4];
    __shared__ u64 red[2][4];
    const int b = blockIdx.x;
    const int tid = threadIdx.x;
    if (b == 0){ stats[tid] = 0.0f; stats[tid + 256] = 0.0f; }   // folded zero_kernel
    const float* xb = xyz + (size_t)b * NN * 3;
    float px[16], py[16], pz[16], dreg[16];
    unsigned int inv[16];
    #pragma unroll
    for (int p = 0; p < 16; ++p){
        int i = tid + p * 256;
        float x = xb[i*3+0], y = xb[i*3+1], z = xb[i*3+2];
        px[p] = x; py[p] = y; pz[p] = z;
        float4 v4; v4.x = x; v4.y = y; v4.z = z; v4.w = 0.0f;
        *((float4*)&xyz4[4*i]) = v4;          // one ds_write_b128
        dreg[p] = 1e10f;                      // ref init 1e10 (exact f32)
        inv[p] = (unsigned int)(NN - 1 - i);  // loop-invariant key low word
    }
    int cur = 0;
    __syncthreads();
    if (tid == 0){  // fps_idx[b,0] == 0 (scan emits carry before update)
        float4 c0 = *((float4*)&xyz4[0]);
        float* of = out + (size_t)b * SS * 3;
        of[0] = c0.x; of[1] = c0.y; of[2] = c0.z;
    }
    const int wave = tid >> 6, lane = tid & 63;
    for (int it = 1; it < SS; ++it){
        float4 c4 = *((float4*)&xyz4[4*cur]);             // single-b128 uniform broadcast
        float cx = c4.x, cy = c4.y, cz = c4.z;
        u64 t[16];
        // strict fp32, no fma contraction: must match numpy's ((dx*dx+dy*dy)+dz*dz) bitwise
        #pragma unroll
        for (int p = 0; p < 16; ++p){
            float dx = __fsub_rn(px[p], cx);
            float dy = __fsub_rn(py[p], cy);
            float dz = __fsub_rn(pz[p], cz);
            float dd = __fadd_rn(__fadd_rn(__fmul_rn(dx,dx), __fmul_rn(dy,dy)),
                                 __fmul_rn(dz,dz));
            dreg[p] = fminf(dreg[p], dd);
            t[p] = ((u64)__float_as_uint(dreg[p]) << 32) | inv[p];
        }
        // pairwise tree (ILP) instead of serial 16-deep chain
        #pragma unroll
        for (int s = 8; s >= 1; s >>= 1)
            #pragma unroll
            for (int i2 = 0; i2 < s; ++i2)
                if (t[i2 + s] > t[i2]) t[i2] = t[i2 + s];
        u64 bk = t[0];
        // DPP reduce over 64 lanes -> winner at lane 63 (VALU pipe, no DS latency)
        FPS_DPP_STEP(0x111)  // row_shr:1
        FPS_DPP_STEP(0x112)  // row_shr:2
        FPS_DPP_STEP(0x114)  // row_shr:4
        FPS_DPP_STEP(0x118)  // row_shr:8  -> lane15 of each row = row max
        FPS_DPP_STEP(0x142)  // row_bcast:15 -> lane31/63 accumulate halves
        FPS_DPP_STEP(0x143)  // row_bcast:31 -> lane63 = wave max
        unsigned int wh = (unsigned int)__builtin_amdgcn_readlane((int)(bk >> 32), 63);
        unsigned int wl = (unsigned int)__builtin_amdgcn_readlane((int)bk, 63);
        if (lane == 0) red[it & 1][wave] = ((u64)wh << 32) | wl;
        __syncthreads();                       // double-buffered red: one barrier/iter
        u64 m0 = red[it & 1][0];
        #pragma unroll
        for (int w = 1; w < 4; ++w){
            u64 o = red[it & 1][w];
            m0 = m0 > o ? m0 : o;
        }
        cur = (NN - 1 - (int)(m0 & 0xffffffffu)) & (NN - 1);
        if (tid == 0){
            float4 n4 = *((float4*)&xyz4[4*cur]);
            float* of = out + ((size_t)b * SS + it) * 3;
            of[0] = n4.x; of[1] = n4.y; of[2] = n4.z;
        }
    }
}

// ---------------- ball query v3: 512-pt super-chunks, pipelined masks ----------------
__global__ __launch_bounds__(256) void ballq_kernel(const float* __restrict__ xyz,
                                                    const float* __restrict__ outc,
                                                    u16* __restrict__ gidx){
    const int g = (blockIdx.x << 2) + (threadIdx.x >> 6);
    const int lane = threadIdx.x & 63;
    const int b = g >> 10;
    const float rr = 0.04f;   // np.float32 promotion of python 0.2*0.2
    const float* c = outc + (size_t)g * 3;
    float cx = c[0], cy = c[1], cz = c[2];
    float sa = __fadd_rn(__fadd_rn(__fmul_rn(cx,cx), __fmul_rn(cy,cy)), __fmul_rn(cz,cz));
    const float* xb = xyz + (size_t)b * NN * 3;
    u16* outp = gidx + (size_t)g * NSAMP;
    int count = 0, first = -1;
    const u64 below = (1ull << lane) - 1ull;
    for (int base = 0; base < NN && count < NSAMP; base += 512){
        u64 masks[8];
        #pragma unroll
        for (int u = 0; u < 8; ++u){          // 8 independent distance+ballot: loads pipeline
            int n = base + u * 64 + lane;
            float x = xb[n*3+0], y = xb[n*3+1], z = xb[n*3+2];
            float sb = __fadd_rn(__fadd_rn(__fmul_rn(x,x), __fmul_rn(y,y)), __fmul_rn(z,z));
            float dt = __fadd_rn(__fadd_rn(__fmul_rn(cx,x), __fmul_rn(cy,y)), __fmul_rn(cz,z));
            float sq = __fadd_rn(__fsub_rn(sa, __fmul_rn(2.0f, dt)), sb);
            masks[u] = __ballot(!(sq > rr));
        }
        #pragma unroll
        for (int u = 0; u < 8; ++u){          // append phase: VALU-only serial chain
            u64 m = masks[u];
            bool w = (m >> lane) & 1ull;
            int pos = __popcll(m & below);
            if (w && (count + pos) < NSAMP) outp[count + pos] = (u16)(base + u * 64 + lane);
            if (first < 0 && m != 0ull) first = base + u * 64 + (__ffsll((long long)m) - 1);
            count += __popcll(m);
        }
    }
    for (int j = count + lane; j < NSAMP; j += 64) outp[j] = (u16)first;
}

// ---------------- shared helpers ----------------
__device__ __forceinline__ void gather_row(const float* __restrict__ xyz, const float* __restrict__ pts,
                                           const float* __restrict__ outc, const u16* __restrict__ gidx,
                                           int row, float* x){
    int g = row >> 5;
    int b = row >> 15;
    int i = gidx[row];
    const float* cc = outc + (size_t)g * 3;
    const float* xp = xyz + ((size_t)b * NN + i) * 3;
    const float* pp = pts + ((size_t)b * NN + i) * 6;
    x[0] = __fsub_rn(xp[0], cc[0]);
    x[1] = __fsub_rn(xp[1], cc[1]);
    x[2] = __fsub_rn(xp[2], cc[2]);
    #pragma unroll
    for (int k = 0; k < 6; ++k) x[3+k] = pp[k];
}

__device__ __forceinline__ void bn_coef(const float* sums, const float* ssqs,
                                        const float* g, const float* bbv, int ch,
                                        float* sc, float* sh){
    float mu = sums[ch] * INV_ROWS;
    float var = fmaf(-mu, mu, ssqs[ch] * INV_ROWS);
    var = fmaxf(var, 0.0f);
    float is = rsqrtf(var + BN_EPS_F);
    float s = is * g[ch];
    sc[ch] = s;
    sh[ch] = fmaf(-mu, s, bbv[ch]);
}

// ---------------- stats1 v2: one row/thread + LDS-transpose reduce ----------------
__global__ __launch_bounds__(256, 1) void stats1_kernel(const float* __restrict__ xyz, const float* __restrict__ pts,
                                                        const float* __restrict__ outc, const u16* __restrict__ gidx,
                                                        const float* __restrict__ W0f, const float* __restrict__ b0f,
                                                        float* __restrict__ stats){
    __shared__ float tr[256 * 65];
    __shared__ float accs[4][64], accq[4][64];
    const int row = blockIdx.x * 256 + threadIdx.x;
    float x[9];
    gather_row(xyz, pts, outc, gidx, row, x);
    #pragma unroll
    for (int j = 0; j < 64; ++j){
        float acc = b0f[j];
        #pragma unroll
        for (int k = 0; k < 9; ++k) acc = fmaf(x[k], W0f[j*9+k], acc);
        tr[threadIdx.x * 65 + j] = acc;
    }
    __syncthreads();
    const int ch = threadIdx.x & 63, qq = threadIdx.x >> 6;
    float s = 0.f, q = 0.f;
    for (int r = 0; r < 64; ++r){
        float v = tr[(qq * 64 + r) * 65 + ch];
        s += v; q = fmaf(v, v, q);
    }
    accs[qq][ch] = s; accq[qq][ch] = q;
    __syncthreads();
    if (threadIdx.x < 64){
        int c = threadIdx.x;
        atomicAdd(&stats[c], (accs[0][c] + accs[1][c]) + (accs[2][c] + accs[3][c]));
    } else if (threadIdx.x < 128){
        int c = threadIdx.x - 64;
        atomicAdd(&stats[64 + c], (accq[0][c] + accq[1][c]) + (accq[2][c] + accq[3][c]));
    }
}

// ---------------- stats2 v3: pk_fma W1 (bitwise-identical accumulation order) ----------------
__global__ __launch_bounds__(256, 1) void stats2_kernel(const float* __restrict__ xyz, const float* __restrict__ pts,
                                                        const float* __restrict__ outc, const u16* __restrict__ gidx,
                                                        const float* __restrict__ W0f, const float* __restrict__ b0f,
                                                        const float* __restrict__ W1f, const float* __restrict__ b1f,
                                                        const float* __restrict__ g0, const float* __restrict__ bb0,
                                                        float* __restrict__ stats){
    __shared__ float sc1[64], sh1[64];
    __shared__ float tr[256 * 65];
    __shared__ float accs[4][64], accq[4][64];
    if (threadIdx.x < 64) bn_coef(stats + 0, stats + 64, g0, bb0, threadIdx.x, sc1, sh1);
    __syncthreads();
    const int row = blockIdx.x * 256 + threadIdx.x;
    float x[9];
    gather_row(xyz, pts, outc, gidx, row, x);
    f32x2 x2p[32];
    #pragma unroll
    for (int j = 0; j < 64; ++j){
        float acc = b0f[j];
        #pragma unroll
        for (int k = 0; k < 9; ++k) acc = fmaf(x[k], W0f[j*9+k], acc);
        float v = fmaxf(fmaf(acc, sc1[j], sh1[j]), 0.f);
        if (j & 1) x2p[j >> 1].y = v; else x2p[j >> 1].x = v;
    }
    // W1: A={a0,a1}, B={a2,a3}; pk pairs (k,k+1)/(k+2,k+3), k+=4 -> same per-acc FMA
    // sequence and same (a0+a1)+(a2+a3) combine as the scalar version: bit-identical.
    for (int ch = 0; ch < 64; ++ch){
        const f32x2* wp = (const f32x2*)(W1f + ch * 64);
        f32x2 A; A.x = b1f[ch]; A.y = 0.f;
        f32x2 B; B.x = 0.f;     B.y = 0.f;
        #pragma unroll
        for (int k2 = 0; k2 < 32; k2 += 2){
            A = pk_fma(x2p[k2],     wp[k2],     A);
            B = pk_fma(x2p[k2 + 1], wp[k2 + 1], B);
        }
        tr[threadIdx.x * 65 + ch] = (A.x + A.y) + (B.x + B.y);
    }
    __syncthreads();
    const int ch = threadIdx.x & 63, qq = threadIdx.x >> 6;
    float s = 0.f, q = 0.f;
    for (int r = 0; r < 64; ++r){
        float v = tr[(qq * 64 + r) * 65 + ch];
        s += v; q = fmaf(v, v, q);
    }
    accs[qq][ch] = s; accq[qq][ch] = q;
    __syncthreads();
    if (threadIdx.x < 64){
        int c = threadIdx.x;
        atomicAdd(&stats[128 + c], (accs[0][c] + accs[1][c]) + (accs[2][c] + accs[3][c]));
    } else if (threadIdx.x < 128){
        int c = threadIdx.x - 64;
        atomicAdd(&stats[192 + c], (accq[0][c] + accq[1][c]) + (accq[2][c] + accq[3][c]));
    }
}

// ---------------- stats3 v3: LDS-staged x3 + pk_fma W1/W2 ----------------
__global__ __launch_bounds__(256, 1) void stats3_kernel(const float* __restrict__ xyz, const float* __restrict__ pts,
                                                        const float* __restrict__ outc, const u16* __restrict__ gidx,
                                                        const float* __restrict__ W0f, const float* __restrict__ b0f,
                                                        const float* __restrict__ W1f, const float* __restrict__ b1f,
                                                        const float* __restrict__ W2f, const float* __restrict__ b2f,
                                                        const float* __restrict__ g0, const float* __restrict__ bb0,
                                                        const float* __restrict__ g1, const float* __restrict__ bb1,
                                                        float* __restrict__ stats,
                                                        float* __restrict__ pmax, float* __restrict__ pmin){
    __shared__ float sc1[64], sh1[64], sc2[64], sh2[64];
    __shared__ float tr[256 * 65];
    __shared__ float accs[4][64], accq[4][64];
    if (threadIdx.x < 64){
        bn_coef(stats + 0,   stats + 64,  g0, bb0, threadIdx.x, sc1, sh1);
        bn_coef(stats + 128, stats + 192, g1, bb1, threadIdx.x, sc2, sh2);
    }
    __syncthreads();
    const int row = blockIdx.x * 256 + threadIdx.x;
    float x[9];
    gather_row(xyz, pts, outc, gidx, row, x);
    f32x2 x2p[32];
    #pragma unroll
    for (int j = 0; j < 64; ++j){
        float acc = b0f[j];
        #pragma unroll
        for (int k = 0; k < 9; ++k) acc = fmaf(x[k], W0f[j*9+k], acc);
        float v = fmaxf(fmaf(acc, sc1[j], sh1[j]), 0.f);
        if (j & 1) x2p[j >> 1].y = v; else x2p[j >> 1].x = v;
    }
    // phase B: x3[j] -> LDS (own row, same-thread RAW; kills x2/x3 dual-liveness spills)
    #pragma unroll
    for (int j = 0; j < 64; ++j){
        const f32x2* wp = (const f32x2*)(W1f + j * 64);
        f32x2 A; A.x = b1f[j]; A.y = 0.f;
        f32x2 B; B.x = 0.f;    B.y = 0.f;
        #pragma unroll
        for (int k2 = 0; k2 < 32; k2 += 2){
            A = pk_fma(x2p[k2],     wp[k2],     A);
            B = pk_fma(x2p[k2 + 1], wp[k2 + 1], B);
        }
        tr[threadIdx.x * 65 + j] = fmaxf(fmaf((A.x + A.y) + (B.x + B.y), sc2[j], sh2[j]), 0.f);
    }
    // compiler barrier: forbid store-to-load forwarding of the staged x3 (which
    // would resurrect the x2+x3 dual-liveness and the spills)
    asm volatile("" ::: "memory");
    f32x2 x3p[32];
    #pragma unroll
    for (int j = 0; j < 32; ++j){
        x3p[j].x = tr[threadIdx.x * 65 + 2*j];
        x3p[j].y = tr[threadIdx.x * 65 + 2*j + 1];
    }
    const int ch = threadIdx.x & 63, qq = threadIdx.x >> 6;
    for (int half = 0; half < 2; ++half){
        for (int c64 = 0; c64 < 64; ++c64){
            int c = half * 64 + c64;
            const f32x2* wp = (const f32x2*)(W2f + c * 64);
            f32x2 A; A.x = b2f[c]; A.y = 0.f;
            f32x2 B; B.x = 0.f;    B.y = 0.f;
            #pragma unroll
            for (int k2 = 0; k2 < 32; k2 += 2){
                A = pk_fma(x3p[k2],     wp[k2],     A);
                B = pk_fma(x3p[k2 + 1], wp[k2 + 1], B);
            }
            tr[threadIdx.x * 65 + c64] = (A.x + A.y) + (B.x + B.y);
        }
        __syncthreads();
        // quarter qq = rows [qq*64, qq*64+64) = groups 2qq (first 32 rows) and 2qq+1
        float s = 0.f, q = 0.f;
        float mxA = -1e30f, mnA = 1e30f, mxB = -1e30f, mnB = 1e30f;
        for (int r = 0; r < 32; ++r){
            float v = tr[(qq * 64 + r) * 65 + ch];
            s += v; q = fmaf(v, v, q);
            mxA = fmaxf(mxA, v); mnA = fminf(mnA, v);
        }
        for (int r = 32; r < 64; ++r){
            float v = tr[(qq * 64 + r) * 65 + ch];
            s += v; q = fmaf(v, v, q);
            mxB = fmaxf(mxB, v); mnB = fminf(mnB, v);
        }
        int c = half * 64 + ch;
        int gA = blockIdx.x * 8 + 2 * qq;
        pmax[(size_t)gA * 128 + c] = mxA;           // coalesced across lanes (c consecutive)
        pmin[(size_t)gA * 128 + c] = mnA;
        pmax[(size_t)(gA + 1) * 128 + c] = mxB;
        pmin[(size_t)(gA + 1) * 128 + c] = mnB;
        accs[qq][ch] = s; accq[qq][ch] = q;
        __syncthreads();
        if (threadIdx.x < 64){
            int cc = half * 64 + threadIdx.x;
            atomicAdd(&stats[256 + cc], (accs[0][threadIdx.x] + accs[1][threadIdx.x])
                                      + (accs[2][threadIdx.x] + accs[3][threadIdx.x]));
        } else if (threadIdx.x < 128){
            int t = threadIdx.x - 64;
            int cc = half * 64 + t;
            atomicAdd(&stats[384 + cc], (accq[0][t] + accq[1][t]) + (accq[2][t] + accq[3][t]));
        }
        __syncthreads();   // tr + accs reuse protection for next half
    }
}

// ---------------- BN3 applied to group max/min, relu, write out region 1 (f32) ----------------
__global__ __launch_bounds__(256) void pool_kernel(const float* __restrict__ stats,
                                                   const float* __restrict__ g2, const float* __restrict__ bb2,
                                                   const float* __restrict__ pmax, const float* __restrict__ pmin,
                                                   float* __restrict__ out){
    __shared__ float sc[128], sh[128];
    if (threadIdx.x < 128) bn_coef(stats + 256, stats + 384, g2, bb2, threadIdx.x, sc, sh);
    __syncthreads();
    int o = blockIdx.x * 256 + threadIdx.x;   // o = g*128 + ch, o < NGRP*128
    int ch = o & 127;
    float a = fmaf(pmax[o], sc[ch], sh[ch]);
    float b = fmaf(pmin[o], sc[ch], sh[ch]);  // affine maps interval endpoints (sc<0 covered)
    out[NGRP * 3 + o] = fmaxf(fmaxf(a, b), 0.0f);
}

extern "C" void kernel_launch(void* const* d_in, const int* in_sizes, int n_in,
                              void* d_out, int out_size, void* d_ws, size_t ws_size,
                              hipStream_t stream){
    const float* xyz = (const float*)d_in[0];
    const float* pts = (const float*)d_in[1];
    const float* W0  = (const float*)d_in[2];
    const float* b0  = (const float*)d_in[3];
    const float* g0  = (const float*)d_in[4];
    const float* bb0 = (const float*)d_in[5];
    const float* W1  = (const float*)d_in[6];
    const float* b1  = (const float*)d_in[7];
    const float* g1  = (const float*)d_in[8];
    const float* bb1 = (const float*)d_in[9];
    const float* W2  = (const float*)d_in[10];
    const float* b2  = (const float*)d_in[11];
    const float* g2  = (const float*)d_in[12];
    const float* bb2 = (const float*)d_in[13];
    float* out = (float*)d_out;   // f32 outputs: [new_xyz 49152 | new_points 2097152]

    // ws layout (bytes): stats[512f]@0 | gidx[524288 u16]@2048 |
    //                    pmax[2097152f]@1050624 | pmin@9439232 ; total 17,827,840
    if (ws_size < 17827840u) return;
    char*  ws    = (char*)d_ws;
    float* stats = (float*)ws;
    u16*   gidx  = (u16*)  (ws + 2048);
    float* pmax  = (float*)(ws + 1050624);
    float* pmin  = (float*)(ws + 9439232);

    fps_kernel  <<<16, 256, 0, stream>>>(xyz, out, stats);   // block 0 also zeroes stats
    ballq_kernel<<<NGRP/4, 256, 0, stream>>>(xyz, out, gidx);
    stats1_kernel<<<ROWS/256, 256, 0, stream>>>(xyz, pts, out, gidx, W0, b0, stats);
    stats2_kernel<<<ROWS/256, 256, 0, stream>>>(xyz, pts, out, gidx, W0, b0, W1, b1, g0, bb0, stats);
    stats3_kernel<<<ROWS/256, 256, 0, stream>>>(xyz, pts, out, gidx, W0, b0, W1, b1, W2, b2,
                                                g0, bb0, g1, bb1, stats, pmax, pmin);
    pool_kernel <<<NGRP*128/256, 256, 0, stream>>>(stats, g2, bb2, pmax, pmin, out);
}

// Round 6
// 1269.928 us; speedup vs baseline: 1.0416x; 1.0055x over previous
//
#include <hip/hip_runtime.h>

typedef unsigned short u16;
typedef unsigned long long u64;
typedef float f32x2 __attribute__((ext_vector_type(2)));

#define NN 4096
#define SS 1024
#define NSAMP 32
#define NGRP 16384            // 16*1024 groups
#define ROWS 524288           // NGRP*NSAMP
#define BN_EPS_F 1e-5f
#define INV_ROWS (1.0f/524288.0f)

// ---------------- packed fp32 FMA (VOP3P) -- throughput kernels only ----------------
// R3 proved: wins in multi-wave throughput kernels (stats2/3, -132us); R4/R5 proved:
// loses or neutral on the fps single-wave latency chain (operand marshaling).
__device__ __forceinline__ f32x2 pk_fma(f32x2 a, f32x2 b, f32x2 c){
    f32x2 d; asm("v_pk_fma_f32 %0, %1, %2, %3" : "=v"(d) : "v"(a), "v"(b), "v"(c)); return d;
}

// ---------------- FPS v7 (best measured 658-662us) + tree merge micro ----------------
// Structural floor analysis (R5): per iter ~440 cyc issue + 2 irreducible LDS round
// trips (~240) + DPP (~110) + barrier. All derived restructurings are net losses
// (R2: 8-wave +81us; R4: pk +55us; R5: b128 +4us). Keep v7 exactly; only the 4-way
// cross-wave merge is upgraded serial->tree (2-deep dep, strictly better ILP).
// Key = (distbits<<32)|(NN-1-idx): exact argmax with first-index tie-break.
#define FPS_DPP_STEP(CTRL)                                                              \
    {   int hs = __builtin_amdgcn_update_dpp((int)(bk >> 32), (int)(bk >> 32),          \
                                             CTRL, 0xf, 0xf, false);                    \
        int ls = __builtin_amdgcn_update_dpp((int)bk, (int)bk, CTRL, 0xf, 0xf, false);  \
        u64 o = ((u64)(unsigned int)hs << 32) | (unsigned int)ls;                       \
        bk = bk > o ? bk : o; }

__global__ __launch_bounds__(256, 1) void fps_kernel(const float* __restrict__ xyz,
                                                     float* __restrict__ out,
                                                     float* __restrict__ stats){
    __shared__ float xs[NN], ys[NN], zs[NN];
    __shared__ u64 red[2][4];
    const int b = blockIdx.x;
    const int tid = threadIdx.x;
    if (b == 0){ stats[tid] = 0.0f; stats[tid + 256] = 0.0f; }   // folded zero_kernel
    const float* xb = xyz + (size_t)b * NN * 3;
    float px[16], py[16], pz[16], dreg[16];
    unsigned int inv[16];
    #pragma unroll
    for (int p = 0; p < 16; ++p){
        int i = tid + p * 256;
        float x = xb[i*3+0], y = xb[i*3+1], z = xb[i*3+2];
        px[p] = x; py[p] = y; pz[p] = z;
        xs[i] = x; ys[i] = y; zs[i] = z;
        dreg[p] = 1e10f;                      // ref init 1e10 (exact f32)
        inv[p] = (unsigned int)(NN - 1 - i);  // loop-invariant key low word
    }
    int cur = 0;
    __syncthreads();
    if (tid == 0){  // fps_idx[b,0] == 0 (scan emits carry before update)
        float* of = out + (size_t)b * SS * 3;
        of[0] = xs[0]; of[1] = ys[0]; of[2] = zs[0];
    }
    const int wave = tid >> 6, lane = tid & 63;
    for (int it = 1; it < SS; ++it){
        float cx = xs[cur], cy = ys[cur], cz = zs[cur];   // uniform LDS broadcast
        u64 t[16];
        // strict fp32, no fma contraction: must match numpy's ((dx*dx+dy*dy)+dz*dz) bitwise
        #pragma unroll
        for (int p = 0; p < 16; ++p){
            float dx = __fsub_rn(px[p], cx);
            float dy = __fsub_rn(py[p], cy);
            float dz = __fsub_rn(pz[p], cz);
            float dd = __fadd_rn(__fadd_rn(__fmul_rn(dx,dx), __fmul_rn(dy,dy)),
                                 __fmul_rn(dz,dz));
            dreg[p] = fminf(dreg[p], dd);
            t[p] = ((u64)__float_as_uint(dreg[p]) << 32) | inv[p];
        }
        // pairwise tree (ILP) instead of serial 16-deep chain
        #pragma unroll
        for (int s = 8; s >= 1; s >>= 1)
            #pragma unroll
            for (int i2 = 0; i2 < s; ++i2)
                if (t[i2 + s] > t[i2]) t[i2] = t[i2 + s];
        u64 bk = t[0];
        // DPP reduce over 64 lanes -> winner at lane 63 (VALU pipe, no DS latency)
        FPS_DPP_STEP(0x111)  // row_shr:1
        FPS_DPP_STEP(0x112)  // row_shr:2
        FPS_DPP_STEP(0x114)  // row_shr:4
        FPS_DPP_STEP(0x118)  // row_shr:8  -> lane15 of each row = row max
        FPS_DPP_STEP(0x142)  // row_bcast:15 -> lane31/63 accumulate halves
        FPS_DPP_STEP(0x143)  // row_bcast:31 -> lane63 = wave max
        unsigned int wh = (unsigned int)__builtin_amdgcn_readlane((int)(bk >> 32), 63);
        unsigned int wl = (unsigned int)__builtin_amdgcn_readlane((int)bk, 63);
        if (lane == 0) red[it & 1][wave] = ((u64)wh << 32) | wl;
        __syncthreads();                       // double-buffered red: one barrier/iter
        u64 r0 = red[it & 1][0], r1 = red[it & 1][1];
        u64 r2 = red[it & 1][2], r3 = red[it & 1][3];
        u64 a01 = r0 > r1 ? r0 : r1;           // pairwise tree: 2-deep dep chain
        u64 a23 = r2 > r3 ? r2 : r3;
        u64 m0  = a01 > a23 ? a01 : a23;
        cur = (NN - 1 - (int)(m0 & 0xffffffffu)) & (NN - 1);
        if (tid == 0){
            float* of = out + ((size_t)b * SS + it) * 3;
            of[0] = xs[cur]; of[1] = ys[cur]; of[2] = zs[cur];
        }
    }
}

// ---------------- ball query v3: 512-pt super-chunks, pipelined masks ----------------
__global__ __launch_bounds__(256) void ballq_kernel(const float* __restrict__ xyz,
                                                    const float* __restrict__ outc,
                                                    u16* __restrict__ gidx){
    const int g = (blockIdx.x << 2) + (threadIdx.x >> 6);
    const int lane = threadIdx.x & 63;
    const int b = g >> 10;
    const float rr = 0.04f;   // np.float32 promotion of python 0.2*0.2
    const float* c = outc + (size_t)g * 3;
    float cx = c[0], cy = c[1], cz = c[2];
    float sa = __fadd_rn(__fadd_rn(__fmul_rn(cx,cx), __fmul_rn(cy,cy)), __fmul_rn(cz,cz));
    const float* xb = xyz + (size_t)b * NN * 3;
    u16* outp = gidx + (size_t)g * NSAMP;
    int count = 0, first = -1;
    const u64 below = (1ull << lane) - 1ull;
    for (int base = 0; base < NN && count < NSAMP; base += 512){
        u64 masks[8];
        #pragma unroll
        for (int u = 0; u < 8; ++u){          // 8 independent distance+ballot: loads pipeline
            int n = base + u * 64 + lane;
            float x = xb[n*3+0], y = xb[n*3+1], z = xb[n*3+2];
            float sb = __fadd_rn(__fadd_rn(__fmul_rn(x,x), __fmul_rn(y,y)), __fmul_rn(z,z));
            float dt = __fadd_rn(__fadd_rn(__fmul_rn(cx,x), __fmul_rn(cy,y)), __fmul_rn(cz,z));
            float sq = __fadd_rn(__fsub_rn(sa, __fmul_rn(2.0f, dt)), sb);
            masks[u] = __ballot(!(sq > rr));
        }
        #pragma unroll
        for (int u = 0; u < 8; ++u){          // append phase: VALU-only serial chain
            u64 m = masks[u];
            bool w = (m >> lane) & 1ull;
            int pos = __popcll(m & below);
            if (w && (count + pos) < NSAMP) outp[count + pos] = (u16)(base + u * 64 + lane);
            if (first < 0 && m != 0ull) first = base + u * 64 + (__ffsll((long long)m) - 1);
            count += __popcll(m);
        }
    }
    for (int j = count + lane; j < NSAMP; j += 64) outp[j] = (u16)first;
}

// ---------------- shared helpers ----------------
__device__ __forceinline__ void gather_row(const float* __restrict__ xyz, const float* __restrict__ pts,
                                           const float* __restrict__ outc, const u16* __restrict__ gidx,
                                           int row, float* x){
    int g = row >> 5;
    int b = row >> 15;
    int i = gidx[row];
    const float* cc = outc + (size_t)g * 3;
    const float* xp = xyz + ((size_t)b * NN + i) * 3;
    const float* pp = pts + ((size_t)b * NN + i) * 6;
    x[0] = __fsub_rn(xp[0], cc[0]);
    x[1] = __fsub_rn(xp[1], cc[1]);
    x[2] = __fsub_rn(xp[2], cc[2]);
    #pragma unroll
    for (int k = 0; k < 6; ++k) x[3+k] = pp[k];
}

__device__ __forceinline__ void bn_coef(const float* sums, const float* ssqs,
                                        const float* g, const float* bbv, int ch,
                                        float* sc, float* sh){
    float mu = sums[ch] * INV_ROWS;
    float var = fmaf(-mu, mu, ssqs[ch] * INV_ROWS);
    var = fmaxf(var, 0.0f);
    float is = rsqrtf(var + BN_EPS_F);
    float s = is * g[ch];
    sc[ch] = s;
    sh[ch] = fmaf(-mu, s, bbv[ch]);
}

// ---------------- stats1 v2: one row/thread + LDS-transpose reduce ----------------
__global__ __launch_bounds__(256, 1) void stats1_kernel(const float* __restrict__ xyz, const float* __restrict__ pts,
                                                        const float* __restrict__ outc, const u16* __restrict__ gidx,
                                                        const float* __restrict__ W0f, const float* __restrict__ b0f,
                                                        float* __restrict__ stats){
    __shared__ float tr[256 * 65];
    __shared__ float accs[4][64], accq[4][64];
    const int row = blockIdx.x * 256 + threadIdx.x;
    float x[9];
    gather_row(xyz, pts, outc, gidx, row, x);
    #pragma unroll
    for (int j = 0; j < 64; ++j){
        float acc = b0f[j];
        #pragma unroll
        for (int k = 0; k < 9; ++k) acc = fmaf(x[k], W0f[j*9+k], acc);
        tr[threadIdx.x * 65 + j] = acc;
    }
    __syncthreads();
    const int ch = threadIdx.x & 63, qq = threadIdx.x >> 6;
    float s = 0.f, q = 0.f;
    for (int r = 0; r < 64; ++r){
        float v = tr[(qq * 64 + r) * 65 + ch];
        s += v; q = fmaf(v, v, q);
    }
    accs[qq][ch] = s; accq[qq][ch] = q;
    __syncthreads();
    if (threadIdx.x < 64){
        int c = threadIdx.x;
        atomicAdd(&stats[c], (accs[0][c] + accs[1][c]) + (accs[2][c] + accs[3][c]));
    } else if (threadIdx.x < 128){
        int c = threadIdx.x - 64;
        atomicAdd(&stats[64 + c], (accq[0][c] + accq[1][c]) + (accq[2][c] + accq[3][c]));
    }
}

// ---------------- stats2 v3: pk_fma W1 (bitwise-identical accumulation order) ----------------
__global__ __launch_bounds__(256, 1) void stats2_kernel(const float* __restrict__ xyz, const float* __restrict__ pts,
                                                        const float* __restrict__ outc, const u16* __restrict__ gidx,
                                                        const float* __restrict__ W0f, const float* __restrict__ b0f,
                                                        const float* __restrict__ W1f, const float* __restrict__ b1f,
                                                        const float* __restrict__ g0, const float* __restrict__ bb0,
                                                        float* __restrict__ stats){
    __shared__ float sc1[64], sh1[64];
    __shared__ float tr[256 * 65];
    __shared__ float accs[4][64], accq[4][64];
    if (threadIdx.x < 64) bn_coef(stats + 0, stats + 64, g0, bb0, threadIdx.x, sc1, sh1);
    __syncthreads();
    const int row = blockIdx.x * 256 + threadIdx.x;
    float x[9];
    gather_row(xyz, pts, outc, gidx, row, x);
    f32x2 x2p[32];
    #pragma unroll
    for (int j = 0; j < 64; ++j){
        float acc = b0f[j];
        #pragma unroll
        for (int k = 0; k < 9; ++k) acc = fmaf(x[k], W0f[j*9+k], acc);
        float v = fmaxf(fmaf(acc, sc1[j], sh1[j]), 0.f);
        if (j & 1) x2p[j >> 1].y = v; else x2p[j >> 1].x = v;
    }
    // W1: A={a0,a1}, B={a2,a3}; pk pairs (k,k+1)/(k+2,k+3), k+=4 -> same per-acc FMA
    // sequence and same (a0+a1)+(a2+a3) combine as the scalar version: bit-identical.
    for (int ch = 0; ch < 64; ++ch){
        const f32x2* wp = (const f32x2*)(W1f + ch * 64);
        f32x2 A; A.x = b1f[ch]; A.y = 0.f;
        f32x2 B; B.x = 0.f;     B.y = 0.f;
        #pragma unroll
        for (int k2 = 0; k2 < 32; k2 += 2){
            A = pk_fma(x2p[k2],     wp[k2],     A);
            B = pk_fma(x2p[k2 + 1], wp[k2 + 1], B);
        }
        tr[threadIdx.x * 65 + ch] = (A.x + A.y) + (B.x + B.y);
    }
    __syncthreads();
    const int ch = threadIdx.x & 63, qq = threadIdx.x >> 6;
    float s = 0.f, q = 0.f;
    for (int r = 0; r < 64; ++r){
        float v = tr[(qq * 64 + r) * 65 + ch];
        s += v; q = fmaf(v, v, q);
    }
    accs[qq][ch] = s; accq[qq][ch] = q;
    __syncthreads();
    if (threadIdx.x < 64){
        int c = threadIdx.x;
        atomicAdd(&stats[128 + c], (accs[0][c] + accs[1][c]) + (accs[2][c] + accs[3][c]));
    } else if (threadIdx.x < 128){
        int c = threadIdx.x - 64;
        atomicAdd(&stats[192 + c], (accq[0][c] + accq[1][c]) + (accq[2][c] + accq[3][c]));
    }
}

// ---------------- stats3 v3: LDS-staged x3 + pk_fma W1/W2 ----------------
__global__ __launch_bounds__(256, 1) void stats3_kernel(const float* __restrict__ xyz, const float* __restrict__ pts,
                                                        const float* __restrict__ outc, const u16* __restrict__ gidx,
                                                        const float* __restrict__ W0f, const float* __restrict__ b0f,
                                                        const float* __restrict__ W1f, const float* __restrict__ b1f,
                                                        const float* __restrict__ W2f, const float* __restrict__ b2f,
                                                        const float* __restrict__ g0, const float* __restrict__ bb0,
                                                        const float* __restrict__ g1, const float* __restrict__ bb1,
                                                        float* __restrict__ stats,
                                                        float* __restrict__ pmax, float* __restrict__ pmin){
    __shared__ float sc1[64], sh1[64], sc2[64], sh2[64];
    __shared__ float tr[256 * 65];
    __shared__ float accs[4][64], accq[4][64];
    if (threadIdx.x < 64){
        bn_coef(stats + 0,   stats + 64,  g0, bb0, threadIdx.x, sc1, sh1);
        bn_coef(stats + 128, stats + 192, g1, bb1, threadIdx.x, sc2, sh2);
    }
    __syncthreads();
    const int row = blockIdx.x * 256 + threadIdx.x;
    float x[9];
    gather_row(xyz, pts, outc, gidx, row, x);
    f32x2 x2p[32];
    #pragma unroll
    for (int j = 0; j < 64; ++j){
        float acc = b0f[j];
        #pragma unroll
        for (int k = 0; k < 9; ++k) acc = fmaf(x[k], W0f[j*9+k], acc);
        float v = fmaxf(fmaf(acc, sc1[j], sh1[j]), 0.f);
        if (j & 1) x2p[j >> 1].y = v; else x2p[j >> 1].x = v;
    }
    // phase B: x3[j] -> LDS (own row, same-thread RAW; kills x2/x3 dual-liveness spills)
    #pragma unroll
    for (int j = 0; j < 64; ++j){
        const f32x2* wp = (const f32x2*)(W1f + j * 64);
        f32x2 A; A.x = b1f[j]; A.y = 0.f;
        f32x2 B; B.x = 0.f;    B.y = 0.f;
        #pragma unroll
        for (int k2 = 0; k2 < 32; k2 += 2){
            A = pk_fma(x2p[k2],     wp[k2],     A);
            B = pk_fma(x2p[k2 + 1], wp[k2 + 1], B);
        }
        tr[threadIdx.x * 65 + j] = fmaxf(fmaf((A.x + A.y) + (B.x + B.y), sc2[j], sh2[j]), 0.f);
    }
    // compiler barrier: forbid store-to-load forwarding of the staged x3 (which
    // would resurrect the x2+x3 dual-liveness and the spills)
    asm volatile("" ::: "memory");
    f32x2 x3p[32];
    #pragma unroll
    for (int j = 0; j < 32; ++j){
        x3p[j].x = tr[threadIdx.x * 65 + 2*j];
        x3p[j].y = tr[threadIdx.x * 65 + 2*j + 1];
    }
    const int ch = threadIdx.x & 63, qq = threadIdx.x >> 6;
    for (int half = 0; half < 2; ++half){
        for (int c64 = 0; c64 < 64; ++c64){
            int c = half * 64 + c64;
            const f32x2* wp = (const f32x2*)(W2f + c * 64);
            f32x2 A; A.x = b2f[c]; A.y = 0.f;
            f32x2 B; B.x = 0.f;    B.y = 0.f;
            #pragma unroll
            for (int k2 = 0; k2 < 32; k2 += 2){
                A = pk_fma(x3p[k2],     wp[k2],     A);
                B = pk_fma(x3p[k2 + 1], wp[k2 + 1], B);
            }
            tr[threadIdx.x * 65 + c64] = (A.x + A.y) + (B.x + B.y);
        }
        __syncthreads();
        // quarter qq = rows [qq*64, qq*64+64) = groups 2qq (first 32 rows) and 2qq+1
        float s = 0.f, q = 0.f;
        float mxA = -1e30f, mnA = 1e30f, mxB = -1e30f, mnB = 1e30f;
        for (int r = 0; r < 32; ++r){
            float v = tr[(qq * 64 + r) * 65 + ch];
            s += v; q = fmaf(v, v, q);
            mxA = fmaxf(mxA, v); mnA = fminf(mnA, v);
        }
        for (int r = 32; r < 64; ++r){
            float v = tr[(qq * 64 + r) * 65 + ch];
            s += v; q = fmaf(v, v, q);
            mxB = fmaxf(mxB, v); mnB = fminf(mnB, v);
        }
        int c = half * 64 + ch;
        int gA = blockIdx.x * 8 + 2 * qq;
        pmax[(size_t)gA * 128 + c] = mxA;           // coalesced across lanes (c consecutive)
        pmin[(size_t)gA * 128 + c] = mnA;
        pmax[(size_t)(gA + 1) * 128 + c] = mxB;
        pmin[(size_t)(gA + 1) * 128 + c] = mnB;
        accs[qq][ch] = s; accq[qq][ch] = q;
        __syncthreads();
        if (threadIdx.x < 64){
            int cc = half * 64 + threadIdx.x;
            atomicAdd(&stats[256 + cc], (accs[0][threadIdx.x] + accs[1][threadIdx.x])
                                      + (accs[2][threadIdx.x] + accs[3][threadIdx.x]));
        } else if (threadIdx.x < 128){
            int t = threadIdx.x - 64;
            int cc = half * 64 + t;
            atomicAdd(&stats[384 + cc], (accq[0][t] + accq[1][t]) + (accq[2][t] + accq[3][t]));
        }
        __syncthreads();   // tr + accs reuse protection for next half
    }
}

// ---------------- BN3 applied to group max/min, relu, write out region 1 (f32) ----------------
__global__ __launch_bounds__(256) void pool_kernel(const float* __restrict__ stats,
                                                   const float* __restrict__ g2, const float* __restrict__ bb2,
                                                   const float* __restrict__ pmax, const float* __restrict__ pmin,
                                                   float* __restrict__ out){
    __shared__ float sc[128], sh[128];
    if (threadIdx.x < 128) bn_coef(stats + 256, stats + 384, g2, bb2, threadIdx.x, sc, sh);
    __syncthreads();
    int o = blockIdx.x * 256 + threadIdx.x;   // o = g*128 + ch, o < NGRP*128
    int ch = o & 127;
    float a = fmaf(pmax[o], sc[ch], sh[ch]);
    float b = fmaf(pmin[o], sc[ch], sh[ch]);  // affine maps interval endpoints (sc<0 covered)
    out[NGRP * 3 + o] = fmaxf(fmaxf(a, b), 0.0f);
}

extern "C" void kernel_launch(void* const* d_in, const int* in_sizes, int n_in,
                              void* d_out, int out_size, void* d_ws, size_t ws_size,
                              hipStream_t stream){
    const float* xyz = (const float*)d_in[0];
    const float* pts = (const float*)d_in[1];
    const float* W0  = (const float*)d_in[2];
    const float* b0  = (const float*)d_in[3];
    const float* g0  = (const float*)d_in[4];
    const float* bb0 = (const float*)d_in[5];
    const float* W1  = (const float*)d_in[6];
    const float* b1  = (const float*)d_in[7];
    const float* g1  = (const float*)d_in[8];
    const float* bb1 = (const float*)d_in[9];
    const float* W2  = (const float*)d_in[10];
    const float* b2  = (const float*)d_in[11];
    const float* g2  = (const float*)d_in[12];
    const float* bb2 = (const float*)d_in[13];
    float* out = (float*)d_out;   // f32 outputs: [new_xyz 49152 | new_points 2097152]

    // ws layout (bytes): stats[512f]@0 | gidx[524288 u16]@2048 |
    //                    pmax[2097152f]@1050624 | pmin@9439232 ; total 17,827,840
    if (ws_size < 17827840u) return;
    char*  ws    = (char*)d_ws;
    float* stats = (float*)ws;
    u16*   gidx  = (u16*)  (ws + 2048);
    float* pmax  = (float*)(ws + 1050624);
    float* pmin  = (float*)(ws + 9439232);

    fps_kernel  <<<16, 256, 0, stream>>>(xyz, out, stats);   // block 0 also zeroes stats
    ballq_kernel<<<NGRP/4, 256, 0, stream>>>(xyz, out, gidx);
    stats1_kernel<<<ROWS/256, 256, 0, stream>>>(xyz, pts, out, gidx, W0, b0, stats);
    stats2_kernel<<<ROWS/256, 256, 0, stream>>>(xyz, pts, out, gidx, W0, b0, W1, b1, g0, bb0, stats);
    stats3_kernel<<<ROWS/256, 256, 0, stream>>>(xyz, pts, out, gidx, W0, b0, W1, b1, W2, b2,
                                                g0, bb0, g1, bb1, stats, pmax, pmin);
    pool_kernel <<<NGRP*128/256, 256, 0, stream>>>(stats, g2, bb2, pmax, pmin, out);
}

// Round 7
// 1235.326 us; speedup vs baseline: 1.0708x; 1.0280x over previous
//
#include <hip/hip_runtime.h>

typedef unsigned short u16;
typedef unsigned long long u64;
typedef float f32x2 __attribute__((ext_vector_type(2)));

#define NN 4096
#define SS 1024
#define NSAMP 32
#define NGRP 16384            // 16*1024 groups
#define ROWS 524288           // NGRP*NSAMP
#define BN_EPS_F 1e-5f
#define INV_ROWS (1.0f/524288.0f)

// ---------------- packed fp32 FMA (VOP3P) -- throughput kernels only ----------------
// R3: pk_fma (all-"v") won -132us in stats2/3. R7: weights are wave-uniform ->
// compiler scalarizes them to SGPR pairs; the all-"v" constraint forced a 64-bit
// s->v marshal (2 v_mov) per pk_fma (3 VALU inst per FMA-pair instead of 1).
// pk_fma_sv takes the weight as the one legal SGPR source of the VOP3P op.
// a*b commutative + per-half rounding -> bit-identical to the all-"v" version.
__device__ __forceinline__ f32x2 pk_fma_sv(f32x2 w, f32x2 x, f32x2 c){
    f32x2 d; asm("v_pk_fma_f32 %0, %1, %2, %3" : "=v"(d) : "s"(w), "v"(x), "v"(c)); return d;
}

// ---------------- FPS v7 (floor ~660-680us; 5 structural attacks all regressed) ----------------
// R2 8-wave: +81us. R4 pk: +55us. R5 b128: +4us. Serial chain: ~500cyc issue +
// 2 LDS round trips + DPP + barrier skew = ~1590cyc/iter, irreducible without
// cross-wave register communication (which gfx950 lacks).
// Key = (distbits<<32)|(NN-1-idx): exact argmax with first-index tie-break.
#define FPS_DPP_STEP(CTRL)                                                              \
    {   int hs = __builtin_amdgcn_update_dpp((int)(bk >> 32), (int)(bk >> 32),          \
                                             CTRL, 0xf, 0xf, false);                    \
        int ls = __builtin_amdgcn_update_dpp((int)bk, (int)bk, CTRL, 0xf, 0xf, false);  \
        u64 o = ((u64)(unsigned int)hs << 32) | (unsigned int)ls;                       \
        bk = bk > o ? bk : o; }

__global__ __launch_bounds__(256, 1) void fps_kernel(const float* __restrict__ xyz,
                                                     float* __restrict__ out,
                                                     float* __restrict__ stats){
    __shared__ float xs[NN], ys[NN], zs[NN];
    __shared__ u64 red[2][4];
    const int b = blockIdx.x;
    const int tid = threadIdx.x;
    if (b == 0){ stats[tid] = 0.0f; stats[tid + 256] = 0.0f; }   // folded zero_kernel
    const float* xb = xyz + (size_t)b * NN * 3;
    float px[16], py[16], pz[16], dreg[16];
    unsigned int inv[16];
    #pragma unroll
    for (int p = 0; p < 16; ++p){
        int i = tid + p * 256;
        float x = xb[i*3+0], y = xb[i*3+1], z = xb[i*3+2];
        px[p] = x; py[p] = y; pz[p] = z;
        xs[i] = x; ys[i] = y; zs[i] = z;
        dreg[p] = 1e10f;                      // ref init 1e10 (exact f32)
        inv[p] = (unsigned int)(NN - 1 - i);  // loop-invariant key low word
    }
    int cur = 0;
    __syncthreads();
    if (tid == 0){  // fps_idx[b,0] == 0 (scan emits carry before update)
        float* of = out + (size_t)b * SS * 3;
        of[0] = xs[0]; of[1] = ys[0]; of[2] = zs[0];
    }
    const int wave = tid >> 6, lane = tid & 63;
    for (int it = 1; it < SS; ++it){
        float cx = xs[cur], cy = ys[cur], cz = zs[cur];   // uniform LDS broadcast
        u64 t[16];
        // strict fp32, no fma contraction: must match numpy's ((dx*dx+dy*dy)+dz*dz) bitwise
        #pragma unroll
        for (int p = 0; p < 16; ++p){
            float dx = __fsub_rn(px[p], cx);
            float dy = __fsub_rn(py[p], cy);
            float dz = __fsub_rn(pz[p], cz);
            float dd = __fadd_rn(__fadd_rn(__fmul_rn(dx,dx), __fmul_rn(dy,dy)),
                                 __fmul_rn(dz,dz));
            dreg[p] = fminf(dreg[p], dd);
            t[p] = ((u64)__float_as_uint(dreg[p]) << 32) | inv[p];
        }
        // pairwise tree (ILP) instead of serial 16-deep chain
        #pragma unroll
        for (int s = 8; s >= 1; s >>= 1)
            #pragma unroll
            for (int i2 = 0; i2 < s; ++i2)
                if (t[i2 + s] > t[i2]) t[i2] = t[i2 + s];
        u64 bk = t[0];
        // DPP reduce over 64 lanes -> winner at lane 63 (VALU pipe, no DS latency)
        FPS_DPP_STEP(0x111)  // row_shr:1
        FPS_DPP_STEP(0x112)  // row_shr:2
        FPS_DPP_STEP(0x114)  // row_shr:4
        FPS_DPP_STEP(0x118)  // row_shr:8  -> lane15 of each row = row max
        FPS_DPP_STEP(0x142)  // row_bcast:15 -> lane31/63 accumulate halves
        FPS_DPP_STEP(0x143)  // row_bcast:31 -> lane63 = wave max
        unsigned int wh = (unsigned int)__builtin_amdgcn_readlane((int)(bk >> 32), 63);
        unsigned int wl = (unsigned int)__builtin_amdgcn_readlane((int)bk, 63);
        if (lane == 0) red[it & 1][wave] = ((u64)wh << 32) | wl;
        __syncthreads();                       // double-buffered red: one barrier/iter
        u64 r0 = red[it & 1][0], r1 = red[it & 1][1];
        u64 r2 = red[it & 1][2], r3 = red[it & 1][3];
        u64 a01 = r0 > r1 ? r0 : r1;           // pairwise tree: 2-deep dep chain
        u64 a23 = r2 > r3 ? r2 : r3;
        u64 m0  = a01 > a23 ? a01 : a23;
        cur = (NN - 1 - (int)(m0 & 0xffffffffu)) & (NN - 1);
        if (tid == 0){
            float* of = out + ((size_t)b * SS + it) * 3;
            of[0] = xs[cur]; of[1] = ys[cur]; of[2] = zs[cur];
        }
    }
}

// ---------------- ball query v3: 512-pt super-chunks, pipelined masks ----------------
__global__ __launch_bounds__(256) void ballq_kernel(const float* __restrict__ xyz,
                                                    const float* __restrict__ outc,
                                                    u16* __restrict__ gidx){
    const int g = (blockIdx.x << 2) + (threadIdx.x >> 6);
    const int lane = threadIdx.x & 63;
    const int b = g >> 10;
    const float rr = 0.04f;   // np.float32 promotion of python 0.2*0.2
    const float* c = outc + (size_t)g * 3;
    float cx = c[0], cy = c[1], cz = c[2];
    float sa = __fadd_rn(__fadd_rn(__fmul_rn(cx,cx), __fmul_rn(cy,cy)), __fmul_rn(cz,cz));
    const float* xb = xyz + (size_t)b * NN * 3;
    u16* outp = gidx + (size_t)g * NSAMP;
    int count = 0, first = -1;
    const u64 below = (1ull << lane) - 1ull;
    for (int base = 0; base < NN && count < NSAMP; base += 512){
        u64 masks[8];
        #pragma unroll
        for (int u = 0; u < 8; ++u){          // 8 independent distance+ballot: loads pipeline
            int n = base + u * 64 + lane;
            float x = xb[n*3+0], y = xb[n*3+1], z = xb[n*3+2];
            float sb = __fadd_rn(__fadd_rn(__fmul_rn(x,x), __fmul_rn(y,y)), __fmul_rn(z,z));
            float dt = __fadd_rn(__fadd_rn(__fmul_rn(cx,x), __fmul_rn(cy,y)), __fmul_rn(cz,z));
            float sq = __fadd_rn(__fsub_rn(sa, __fmul_rn(2.0f, dt)), sb);
            masks[u] = __ballot(!(sq > rr));
        }
        #pragma unroll
        for (int u = 0; u < 8; ++u){          // append phase: VALU-only serial chain
            u64 m = masks[u];
            bool w = (m >> lane) & 1ull;
            int pos = __popcll(m & below);
            if (w && (count + pos) < NSAMP) outp[count + pos] = (u16)(base + u * 64 + lane);
            if (first < 0 && m != 0ull) first = base + u * 64 + (__ffsll((long long)m) - 1);
            count += __popcll(m);
        }
    }
    for (int j = count + lane; j < NSAMP; j += 64) outp[j] = (u16)first;
}

// ---------------- shared helpers ----------------
__device__ __forceinline__ void gather_row(const float* __restrict__ xyz, const float* __restrict__ pts,
                                           const float* __restrict__ outc, const u16* __restrict__ gidx,
                                           int row, float* x){
    int g = row >> 5;
    int b = row >> 15;
    int i = gidx[row];
    const float* cc = outc + (size_t)g * 3;
    const float* xp = xyz + ((size_t)b * NN + i) * 3;
    const float* pp = pts + ((size_t)b * NN + i) * 6;
    x[0] = __fsub_rn(xp[0], cc[0]);
    x[1] = __fsub_rn(xp[1], cc[1]);
    x[2] = __fsub_rn(xp[2], cc[2]);
    #pragma unroll
    for (int k = 0; k < 6; ++k) x[3+k] = pp[k];
}

__device__ __forceinline__ void bn_coef(const float* sums, const float* ssqs,
                                        const float* g, const float* bbv, int ch,
                                        float* sc, float* sh){
    float mu = sums[ch] * INV_ROWS;
    float var = fmaf(-mu, mu, ssqs[ch] * INV_ROWS);
    var = fmaxf(var, 0.0f);
    float is = rsqrtf(var + BN_EPS_F);
    float s = is * g[ch];
    sc[ch] = s;
    sh[ch] = fmaf(-mu, s, bbv[ch]);
}

// ---------------- stats1 v2: one row/thread + LDS-transpose reduce ----------------
// W0 loads are uniform -> compiler already uses s_load + v_fma with direct SGPR
// operand (VOP3 allows 1 SGPR src): no marshal overhead, leave scalar.
__global__ __launch_bounds__(256, 1) void stats1_kernel(const float* __restrict__ xyz, const float* __restrict__ pts,
                                                        const float* __restrict__ outc, const u16* __restrict__ gidx,
                                                        const float* __restrict__ W0f, const float* __restrict__ b0f,
                                                        float* __restrict__ stats){
    __shared__ float tr[256 * 65];
    __shared__ float accs[4][64], accq[4][64];
    const int row = blockIdx.x * 256 + threadIdx.x;
    float x[9];
    gather_row(xyz, pts, outc, gidx, row, x);
    #pragma unroll
    for (int j = 0; j < 64; ++j){
        float acc = b0f[j];
        #pragma unroll
        for (int k = 0; k < 9; ++k) acc = fmaf(x[k], W0f[j*9+k], acc);
        tr[threadIdx.x * 65 + j] = acc;
    }
    __syncthreads();
    const int ch = threadIdx.x & 63, qq = threadIdx.x >> 6;
    float s = 0.f, q = 0.f;
    for (int r = 0; r < 64; ++r){
        float v = tr[(qq * 64 + r) * 65 + ch];
        s += v; q = fmaf(v, v, q);
    }
    accs[qq][ch] = s; accq[qq][ch] = q;
    __syncthreads();
    if (threadIdx.x < 64){
        int c = threadIdx.x;
        atomicAdd(&stats[c], (accs[0][c] + accs[1][c]) + (accs[2][c] + accs[3][c]));
    } else if (threadIdx.x < 128){
        int c = threadIdx.x - 64;
        atomicAdd(&stats[64 + c], (accq[0][c] + accq[1][c]) + (accq[2][c] + accq[3][c]));
    }
}

// ---------------- stats2 v4: pk_fma with SGPR weight source ----------------
__global__ __launch_bounds__(256, 1) void stats2_kernel(const float* __restrict__ xyz, const float* __restrict__ pts,
                                                        const float* __restrict__ outc, const u16* __restrict__ gidx,
                                                        const float* __restrict__ W0f, const float* __restrict__ b0f,
                                                        const float* __restrict__ W1f, const float* __restrict__ b1f,
                                                        const float* __restrict__ g0, const float* __restrict__ bb0,
                                                        float* __restrict__ stats){
    __shared__ float sc1[64], sh1[64];
    __shared__ float tr[256 * 65];
    __shared__ float accs[4][64], accq[4][64];
    if (threadIdx.x < 64) bn_coef(stats + 0, stats + 64, g0, bb0, threadIdx.x, sc1, sh1);
    __syncthreads();
    const int row = blockIdx.x * 256 + threadIdx.x;
    float x[9];
    gather_row(xyz, pts, outc, gidx, row, x);
    f32x2 x2p[32];
    #pragma unroll
    for (int j = 0; j < 64; ++j){
        float acc = b0f[j];
        #pragma unroll
        for (int k = 0; k < 9; ++k) acc = fmaf(x[k], W0f[j*9+k], acc);
        float v = fmaxf(fmaf(acc, sc1[j], sh1[j]), 0.f);
        if (j & 1) x2p[j >> 1].y = v; else x2p[j >> 1].x = v;
    }
    // W1: A={a0,a1}, B={a2,a3}; pk pairs (k,k+1)/(k+2,k+3), k+=4 -> same per-acc FMA
    // sequence and same (a0+a1)+(a2+a3) combine as the scalar version: bit-identical.
    for (int ch = 0; ch < 64; ++ch){
        const f32x2* wp = (const f32x2*)(W1f + ch * 64);
        f32x2 A; A.x = b1f[ch]; A.y = 0.f;
        f32x2 B; B.x = 0.f;     B.y = 0.f;
        #pragma unroll
        for (int k2 = 0; k2 < 32; k2 += 2){
            A = pk_fma_sv(wp[k2],     x2p[k2],     A);
            B = pk_fma_sv(wp[k2 + 1], x2p[k2 + 1], B);
        }
        tr[threadIdx.x * 65 + ch] = (A.x + A.y) + (B.x + B.y);
    }
    __syncthreads();
    const int ch = threadIdx.x & 63, qq = threadIdx.x >> 6;
    float s = 0.f, q = 0.f;
    for (int r = 0; r < 64; ++r){
        float v = tr[(qq * 64 + r) * 65 + ch];
        s += v; q = fmaf(v, v, q);
    }
    accs[qq][ch] = s; accq[qq][ch] = q;
    __syncthreads();
    if (threadIdx.x < 64){
        int c = threadIdx.x;
        atomicAdd(&stats[128 + c], (accs[0][c] + accs[1][c]) + (accs[2][c] + accs[3][c]));
    } else if (threadIdx.x < 128){
        int c = threadIdx.x - 64;
        atomicAdd(&stats[192 + c], (accq[0][c] + accq[1][c]) + (accq[2][c] + accq[3][c]));
    }
}

// ---------------- stats3 v4: LDS-staged x3 + pk_fma with SGPR weight source ----------------
__global__ __launch_bounds__(256, 1) void stats3_kernel(const float* __restrict__ xyz, const float* __restrict__ pts,
                                                        const float* __restrict__ outc, const u16* __restrict__ gidx,
                                                        const float* __restrict__ W0f, const float* __restrict__ b0f,
                                                        const float* __restrict__ W1f, const float* __restrict__ b1f,
                                                        const float* __restrict__ W2f, const float* __restrict__ b2f,
                                                        const float* __restrict__ g0, const float* __restrict__ bb0,
                                                        const float* __restrict__ g1, const float* __restrict__ bb1,
                                                        float* __restrict__ stats,
                                                        float* __restrict__ pmax, float* __restrict__ pmin){
    __shared__ float sc1[64], sh1[64], sc2[64], sh2[64];
    __shared__ float tr[256 * 65];
    __shared__ float accs[4][64], accq[4][64];
    if (threadIdx.x < 64){
        bn_coef(stats + 0,   stats + 64,  g0, bb0, threadIdx.x, sc1, sh1);
        bn_coef(stats + 128, stats + 192, g1, bb1, threadIdx.x, sc2, sh2);
    }
    __syncthreads();
    const int row = blockIdx.x * 256 + threadIdx.x;
    float x[9];
    gather_row(xyz, pts, outc, gidx, row, x);
    f32x2 x2p[32];
    #pragma unroll
    for (int j = 0; j < 64; ++j){
        float acc = b0f[j];
        #pragma unroll
        for (int k = 0; k < 9; ++k) acc = fmaf(x[k], W0f[j*9+k], acc);
        float v = fmaxf(fmaf(acc, sc1[j], sh1[j]), 0.f);
        if (j & 1) x2p[j >> 1].y = v; else x2p[j >> 1].x = v;
    }
    // phase B: x3[j] -> LDS (own row, same-thread RAW; kills x2/x3 dual-liveness spills)
    #pragma unroll
    for (int j = 0; j < 64; ++j){
        const f32x2* wp = (const f32x2*)(W1f + j * 64);
        f32x2 A; A.x = b1f[j]; A.y = 0.f;
        f32x2 B; B.x = 0.f;    B.y = 0.f;
        #pragma unroll
        for (int k2 = 0; k2 < 32; k2 += 2){
            A = pk_fma_sv(wp[k2],     x2p[k2],     A);
            B = pk_fma_sv(wp[k2 + 1], x2p[k2 + 1], B);
        }
        tr[threadIdx.x * 65 + j] = fmaxf(fmaf((A.x + A.y) + (B.x + B.y), sc2[j], sh2[j]), 0.f);
    }
    // compiler barrier: forbid store-to-load forwarding of the staged x3 (which
    // would resurrect the x2+x3 dual-liveness and the spills)
    asm volatile("" ::: "memory");
    f32x2 x3p[32];
    #pragma unroll
    for (int j = 0; j < 32; ++j){
        x3p[j].x = tr[threadIdx.x * 65 + 2*j];
        x3p[j].y = tr[threadIdx.x * 65 + 2*j + 1];
    }
    const int ch = threadIdx.x & 63, qq = threadIdx.x >> 6;
    for (int half = 0; half < 2; ++half){
        for (int c64 = 0; c64 < 64; ++c64){
            int c = half * 64 + c64;
            const f32x2* wp = (const f32x2*)(W2f + c * 64);
            f32x2 A; A.x = b2f[c]; A.y = 0.f;
            f32x2 B; B.x = 0.f;    B.y = 0.f;
            #pragma unroll
            for (int k2 = 0; k2 < 32; k2 += 2){
                A = pk_fma_sv(wp[k2],     x3p[k2],     A);
                B = pk_fma_sv(wp[k2 + 1], x3p[k2 + 1], B);
            }
            tr[threadIdx.x * 65 + c64] = (A.x + A.y) + (B.x + B.y);
        }
        __syncthreads();
        // quarter qq = rows [qq*64, qq*64+64) = groups 2qq (first 32 rows) and 2qq+1
        float s = 0.f, q = 0.f;
        float mxA = -1e30f, mnA = 1e30f, mxB = -1e30f, mnB = 1e30f;
        for (int r = 0; r < 32; ++r){
            float v = tr[(qq * 64 + r) * 65 + ch];
            s += v; q = fmaf(v, v, q);
            mxA = fmaxf(mxA, v); mnA = fminf(mnA, v);
        }
        for (int r = 32; r < 64; ++r){
            float v = tr[(qq * 64 + r) * 65 + ch];
            s += v; q = fmaf(v, v, q);
            mxB = fmaxf(mxB, v); mnB = fminf(mnB, v);
        }
        int c = half * 64 + ch;
        int gA = blockIdx.x * 8 + 2 * qq;
        pmax[(size_t)gA * 128 + c] = mxA;           // coalesced across lanes (c consecutive)
        pmin[(size_t)gA * 128 + c] = mnA;
        pmax[(size_t)(gA + 1) * 128 + c] = mxB;
        pmin[(size_t)(gA + 1) * 128 + c] = mnB;
        accs[qq][ch] = s; accq[qq][ch] = q;
        __syncthreads();
        if (threadIdx.x < 64){
            int cc = half * 64 + threadIdx.x;
            atomicAdd(&stats[256 + cc], (accs[0][threadIdx.x] + accs[1][threadIdx.x])
                                      + (accs[2][threadIdx.x] + accs[3][threadIdx.x]));
        } else if (threadIdx.x < 128){
            int t = threadIdx.x - 64;
            int cc = half * 64 + t;
            atomicAdd(&stats[384 + cc], (accq[0][t] + accq[1][t]) + (accq[2][t] + accq[3][t]));
        }
        __syncthreads();   // tr + accs reuse protection for next half
    }
}

// ---------------- BN3 applied to group max/min, relu, write out region 1 (f32) ----------------
__global__ __launch_bounds__(256) void pool_kernel(const float* __restrict__ stats,
                                                   const float* __restrict__ g2, const float* __restrict__ bb2,
                                                   const float* __restrict__ pmax, const float* __restrict__ pmin,
                                                   float* __restrict__ out){
    __shared__ float sc[128], sh[128];
    if (threadIdx.x < 128) bn_coef(stats + 256, stats + 384, g2, bb2, threadIdx.x, sc, sh);
    __syncthreads();
    int o = blockIdx.x * 256 + threadIdx.x;   // o = g*128 + ch, o < NGRP*128
    int ch = o & 127;
    float a = fmaf(pmax[o], sc[ch], sh[ch]);
    float b = fmaf(pmin[o], sc[ch], sh[ch]);  // affine maps interval endpoints (sc<0 covered)
    out[NGRP * 3 + o] = fmaxf(fmaxf(a, b), 0.0f);
}

extern "C" void kernel_launch(void* const* d_in, const int* in_sizes, int n_in,
                              void* d_out, int out_size, void* d_ws, size_t ws_size,
                              hipStream_t stream){
    const float* xyz = (const float*)d_in[0];
    const float* pts = (const float*)d_in[1];
    const float* W0  = (const float*)d_in[2];
    const float* b0  = (const float*)d_in[3];
    const float* g0  = (const float*)d_in[4];
    const float* bb0 = (const float*)d_in[5];
    const float* W1  = (const float*)d_in[6];
    const float* b1  = (const float*)d_in[7];
    const float* g1  = (const float*)d_in[8];
    const float* bb1 = (const float*)d_in[9];
    const float* W2  = (const float*)d_in[10];
    const float* b2  = (const float*)d_in[11];
    const float* g2  = (const float*)d_in[12];
    const float* bb2 = (const float*)d_in[13];
    float* out = (float*)d_out;   // f32 outputs: [new_xyz 49152 | new_points 2097152]

    // ws layout (bytes): stats[512f]@0 | gidx[524288 u16]@2048 |
    //                    pmax[2097152f]@1050624 | pmin@9439232 ; total 17,827,840
    if (ws_size < 17827840u) return;
    char*  ws    = (char*)d_ws;
    float* stats = (float*)ws;
    u16*   gidx  = (u16*)  (ws + 2048);
    float* pmax  = (float*)(ws + 1050624);
    float* pmin  = (float*)(ws + 9439232);

    fps_kernel  <<<16, 256, 0, stream>>>(xyz, out, stats);   // block 0 also zeroes stats
    ballq_kernel<<<NGRP/4, 256, 0, stream>>>(xyz, out, gidx);
    stats1_kernel<<<ROWS/256, 256, 0, stream>>>(xyz, pts, out, gidx, W0, b0, stats);
    stats2_kernel<<<ROWS/256, 256, 0, stream>>>(xyz, pts, out, gidx, W0, b0, W1, b1, g0, bb0, stats);
    stats3_kernel<<<ROWS/256, 256, 0, stream>>>(xyz, pts, out, gidx, W0, b0, W1, b1, W2, b2,
                                                g0, bb0, g1, bb1, stats, pmax, pmin);
    pool_kernel <<<NGRP*128/256, 256, 0, stream>>>(stats, g2, bb2, pmax, pmin, out);
}

// Round 8
// 1085.680 us; speedup vs baseline: 1.2184x; 1.1378x over previous
//
#include <hip/hip_runtime.h>

typedef unsigned short u16;
typedef unsigned long long u64;
typedef float f32x2 __attribute__((ext_vector_type(2)));

#define NN 4096
#define SS 1024
#define NSAMP 32
#define NGRP 16384            // 16*1024 groups
#define ROWS 524288           // NGRP*NSAMP
#define BN_EPS_F 1e-5f
#define INV_ROWS (1.0f/524288.0f)

// ---------------- packed fp32 FMA (VOP3P), weight in the one legal SGPR slot ----------------
// R3: pk_fma -132us (stats2/3). R7: SGPR-weight source -35us (kills s->v marshal).
__device__ __forceinline__ f32x2 pk_fma_sv(f32x2 w, f32x2 x, f32x2 c){
    f32x2 d; asm("v_pk_fma_f32 %0, %1, %2, %3" : "=v"(d) : "s"(w), "v"(x), "v"(c)); return d;
}

// ---------------- FPS v7 (floor ~660-680us; 5 structural attacks all regressed) ----------------
// R2 8-wave: +81us. R4 pk: +55us. R5 b128: +4us. Serial chain: ~460cyc issue +
// 2 LDS round trips + DPP + barrier skew ~= 1590cyc/iter; irreducible without
// cross-wave register communication (which gfx950 lacks).
// Key = (distbits<<32)|(NN-1-idx): exact argmax with first-index tie-break.
#define FPS_DPP_STEP(CTRL)                                                              \
    {   int hs = __builtin_amdgcn_update_dpp((int)(bk >> 32), (int)(bk >> 32),          \
                                             CTRL, 0xf, 0xf, false);                    \
        int ls = __builtin_amdgcn_update_dpp((int)bk, (int)bk, CTRL, 0xf, 0xf, false);  \
        u64 o = ((u64)(unsigned int)hs << 32) | (unsigned int)ls;                       \
        bk = bk > o ? bk : o; }

__global__ __launch_bounds__(256, 1) void fps_kernel(const float* __restrict__ xyz,
                                                     float* __restrict__ out,
                                                     float* __restrict__ stats){
    __shared__ float xs[NN], ys[NN], zs[NN];
    __shared__ u64 red[2][4];
    const int b = blockIdx.x;
    const int tid = threadIdx.x;
    if (b == 0){ stats[tid] = 0.0f; stats[tid + 256] = 0.0f; }   // folded zero_kernel
    const float* xb = xyz + (size_t)b * NN * 3;
    float px[16], py[16], pz[16], dreg[16];
    unsigned int inv[16];
    #pragma unroll
    for (int p = 0; p < 16; ++p){
        int i = tid + p * 256;
        float x = xb[i*3+0], y = xb[i*3+1], z = xb[i*3+2];
        px[p] = x; py[p] = y; pz[p] = z;
        xs[i] = x; ys[i] = y; zs[i] = z;
        dreg[p] = 1e10f;                      // ref init 1e10 (exact f32)
        inv[p] = (unsigned int)(NN - 1 - i);  // loop-invariant key low word
    }
    int cur = 0;
    __syncthreads();
    if (tid == 0){  // fps_idx[b,0] == 0 (scan emits carry before update)
        float* of = out + (size_t)b * SS * 3;
        of[0] = xs[0]; of[1] = ys[0]; of[2] = zs[0];
    }
    const int wave = tid >> 6, lane = tid & 63;
    for (int it = 1; it < SS; ++it){
        float cx = xs[cur], cy = ys[cur], cz = zs[cur];   // uniform LDS broadcast
        u64 t[16];
        // strict fp32, no fma contraction: must match numpy's ((dx*dx+dy*dy)+dz*dz) bitwise
        #pragma unroll
        for (int p = 0; p < 16; ++p){
            float dx = __fsub_rn(px[p], cx);
            float dy = __fsub_rn(py[p], cy);
            float dz = __fsub_rn(pz[p], cz);
            float dd = __fadd_rn(__fadd_rn(__fmul_rn(dx,dx), __fmul_rn(dy,dy)),
                                 __fmul_rn(dz,dz));
            dreg[p] = fminf(dreg[p], dd);
            t[p] = ((u64)__float_as_uint(dreg[p]) << 32) | inv[p];
        }
        // pairwise tree (ILP) instead of serial 16-deep chain
        #pragma unroll
        for (int s = 8; s >= 1; s >>= 1)
            #pragma unroll
            for (int i2 = 0; i2 < s; ++i2)
                if (t[i2 + s] > t[i2]) t[i2] = t[i2 + s];
        u64 bk = t[0];
        // DPP reduce over 64 lanes -> winner at lane 63 (VALU pipe, no DS latency)
        FPS_DPP_STEP(0x111)  // row_shr:1
        FPS_DPP_STEP(0x112)  // row_shr:2
        FPS_DPP_STEP(0x114)  // row_shr:4
        FPS_DPP_STEP(0x118)  // row_shr:8  -> lane15 of each row = row max
        FPS_DPP_STEP(0x142)  // row_bcast:15 -> lane31/63 accumulate halves
        FPS_DPP_STEP(0x143)  // row_bcast:31 -> lane63 = wave max
        unsigned int wh = (unsigned int)__builtin_amdgcn_readlane((int)(bk >> 32), 63);
        unsigned int wl = (unsigned int)__builtin_amdgcn_readlane((int)bk, 63);
        if (lane == 0) red[it & 1][wave] = ((u64)wh << 32) | wl;
        __syncthreads();                       // double-buffered red: one barrier/iter
        u64 r0 = red[it & 1][0], r1 = red[it & 1][1];
        u64 r2 = red[it & 1][2], r3 = red[it & 1][3];
        u64 a01 = r0 > r1 ? r0 : r1;           // pairwise tree: 2-deep dep chain
        u64 a23 = r2 > r3 ? r2 : r3;
        u64 m0  = a01 > a23 ? a01 : a23;
        cur = (NN - 1 - (int)(m0 & 0xffffffffu)) & (NN - 1);
        if (tid == 0){
            float* of = out + ((size_t)b * SS + it) * 3;
            of[0] = xs[cur]; of[1] = ys[cur]; of[2] = zs[cur];
        }
    }
}

// ---------------- ball query v3: 512-pt super-chunks, pipelined masks ----------------
__global__ __launch_bounds__(256) void ballq_kernel(const float* __restrict__ xyz,
                                                    const float* __restrict__ outc,
                                                    u16* __restrict__ gidx){
    const int g = (blockIdx.x << 2) + (threadIdx.x >> 6);
    const int lane = threadIdx.x & 63;
    const int b = g >> 10;
    const float rr = 0.04f;   // np.float32 promotion of python 0.2*0.2
    const float* c = outc + (size_t)g * 3;
    float cx = c[0], cy = c[1], cz = c[2];
    float sa = __fadd_rn(__fadd_rn(__fmul_rn(cx,cx), __fmul_rn(cy,cy)), __fmul_rn(cz,cz));
    const float* xb = xyz + (size_t)b * NN * 3;
    u16* outp = gidx + (size_t)g * NSAMP;
    int count = 0, first = -1;
    const u64 below = (1ull << lane) - 1ull;
    for (int base = 0; base < NN && count < NSAMP; base += 512){
        u64 masks[8];
        #pragma unroll
        for (int u = 0; u < 8; ++u){          // 8 independent distance+ballot: loads pipeline
            int n = base + u * 64 + lane;
            float x = xb[n*3+0], y = xb[n*3+1], z = xb[n*3+2];
            float sb = __fadd_rn(__fadd_rn(__fmul_rn(x,x), __fmul_rn(y,y)), __fmul_rn(z,z));
            float dt = __fadd_rn(__fadd_rn(__fmul_rn(cx,x), __fmul_rn(cy,y)), __fmul_rn(cz,z));
            float sq = __fadd_rn(__fsub_rn(sa, __fmul_rn(2.0f, dt)), sb);
            masks[u] = __ballot(!(sq > rr));
        }
        #pragma unroll
        for (int u = 0; u < 8; ++u){          // append phase: VALU-only serial chain
            u64 m = masks[u];
            bool w = (m >> lane) & 1ull;
            int pos = __popcll(m & below);
            if (w && (count + pos) < NSAMP) outp[count + pos] = (u16)(base + u * 64 + lane);
            if (first < 0 && m != 0ull) first = base + u * 64 + (__ffsll((long long)m) - 1);
            count += __popcll(m);
        }
    }
    for (int j = count + lane; j < NSAMP; j += 64) outp[j] = (u16)first;
}

// ---------------- shared helpers ----------------
__device__ __forceinline__ void gather_row(const float* __restrict__ xyz, const float* __restrict__ pts,
                                           const float* __restrict__ outc, const u16* __restrict__ gidx,
                                           int row, float* x){
    int g = row >> 5;
    int b = row >> 15;
    int i = gidx[row];
    const float* cc = outc + (size_t)g * 3;
    const float* xp = xyz + ((size_t)b * NN + i) * 3;
    const float* pp = pts + ((size_t)b * NN + i) * 6;
    x[0] = __fsub_rn(xp[0], cc[0]);
    x[1] = __fsub_rn(xp[1], cc[1]);
    x[2] = __fsub_rn(xp[2], cc[2]);
    #pragma unroll
    for (int k = 0; k < 6; ++k) x[3+k] = pp[k];
}

__device__ __forceinline__ void bn_coef(const float* sums, const float* ssqs,
                                        const float* g, const float* bbv, int ch,
                                        float* sc, float* sh){
    float mu = sums[ch] * INV_ROWS;
    float var = fmaf(-mu, mu, ssqs[ch] * INV_ROWS);
    var = fmaxf(var, 0.0f);
    float is = rsqrtf(var + BN_EPS_F);
    float s = is * g[ch];
    sc[ch] = s;
    sh[ch] = fmaf(-mu, s, bbv[ch]);
}

// ================= R8: occupancy attack on the stats passes =================
// The 66.5KB tr[256*65] capped every stats kernel at 2 blocks/CU (2 waves/SIMD)
// -- too thin to hide gather + s_load + barrier latency (issue math predicts
// ~75us total VALU; measured rest ~557us). Split the channel transpose into two
// 32-channel passes: tr[256*33]=33.8KB -> 4 blocks/CU. Per-channel FMA chains
// are bit-identical; only the partial-sum combine tree changes (8x32-row vs
// 4x64-row partials) -- legal, stats accumulation is already atomic-order-
// nondeterministic. Octant o = tid>>5 covers rows o*32..o*32+31 = exactly one
// ball-query group -> pmax/pmin chains stay bit-identical too.

// ---------------- stats1 v3: 2-pass 32-ch transpose, 4 blocks/CU ----------------
__global__ __launch_bounds__(256, 4) void stats1_kernel(const float* __restrict__ xyz, const float* __restrict__ pts,
                                                        const float* __restrict__ outc, const u16* __restrict__ gidx,
                                                        const float* __restrict__ W0f, const float* __restrict__ b0f,
                                                        float* __restrict__ stats){
    __shared__ float tr[256 * 33];
    __shared__ float accs[8][32], accq[8][32];
    const int row = blockIdx.x * 256 + threadIdx.x;
    float x[9];
    gather_row(xyz, pts, outc, gidx, row, x);
    const int ch = threadIdx.x & 31, oc = threadIdx.x >> 5;
    #pragma unroll
    for (int h2 = 0; h2 < 2; ++h2){
        #pragma unroll
        for (int j = 0; j < 32; ++j){
            int jj = h2 * 32 + j;
            float acc = b0f[jj];
            #pragma unroll
            for (int k = 0; k < 9; ++k) acc = fmaf(x[k], W0f[jj*9+k], acc);
            tr[threadIdx.x * 33 + j] = acc;
        }
        __syncthreads();
        float s = 0.f, q = 0.f;
        for (int r = 0; r < 32; ++r){
            float v = tr[(oc * 32 + r) * 33 + ch];
            s += v; q = fmaf(v, v, q);
        }
        accs[oc][ch] = s; accq[oc][ch] = q;
        __syncthreads();
        if (threadIdx.x < 32){
            int t = threadIdx.x;
            float t0 = (accs[0][t] + accs[1][t]) + (accs[2][t] + accs[3][t]);
            float t1 = (accs[4][t] + accs[5][t]) + (accs[6][t] + accs[7][t]);
            atomicAdd(&stats[h2 * 32 + t], t0 + t1);
        } else if (threadIdx.x < 64){
            int t = threadIdx.x - 32;
            float t0 = (accq[0][t] + accq[1][t]) + (accq[2][t] + accq[3][t]);
            float t1 = (accq[4][t] + accq[5][t]) + (accq[6][t] + accq[7][t]);
            atomicAdd(&stats[64 + h2 * 32 + t], t0 + t1);
        }
        __syncthreads();   // tr/accs reuse protection before next half
    }
}

// ---------------- stats2 v5: pk_fma_sv W1, 2-pass 32-ch transpose ----------------
__global__ __launch_bounds__(256, 4) void stats2_kernel(const float* __restrict__ xyz, const float* __restrict__ pts,
                                                        const float* __restrict__ outc, const u16* __restrict__ gidx,
                                                        const float* __restrict__ W0f, const float* __restrict__ b0f,
                                                        const float* __restrict__ W1f, const float* __restrict__ b1f,
                                                        const float* __restrict__ g0, const float* __restrict__ bb0,
                                                        float* __restrict__ stats){
    __shared__ float sc1[64], sh1[64];
    __shared__ float tr[256 * 33];
    __shared__ float accs[8][32], accq[8][32];
    if (threadIdx.x < 64) bn_coef(stats + 0, stats + 64, g0, bb0, threadIdx.x, sc1, sh1);
    __syncthreads();
    const int row = blockIdx.x * 256 + threadIdx.x;
    float x[9];
    gather_row(xyz, pts, outc, gidx, row, x);
    f32x2 x2p[32];
    #pragma unroll
    for (int j = 0; j < 64; ++j){
        float acc = b0f[j];
        #pragma unroll
        for (int k = 0; k < 9; ++k) acc = fmaf(x[k], W0f[j*9+k], acc);
        float v = fmaxf(fmaf(acc, sc1[j], sh1[j]), 0.f);
        if (j & 1) x2p[j >> 1].y = v; else x2p[j >> 1].x = v;
    }
    const int ch = threadIdx.x & 31, oc = threadIdx.x >> 5;
    #pragma unroll
    for (int h2 = 0; h2 < 2; ++h2){
        // A gets even pk-pairs, B odd -> same per-acc FMA sequence as scalar a0..a3
        for (int chh = 0; chh < 32; ++chh){
            int c = h2 * 32 + chh;
            const f32x2* wp = (const f32x2*)(W1f + c * 64);
            f32x2 A; A.x = b1f[c]; A.y = 0.f;
            f32x2 B; B.x = 0.f;    B.y = 0.f;
            #pragma unroll
            for (int k2 = 0; k2 < 32; k2 += 2){
                A = pk_fma_sv(wp[k2],     x2p[k2],     A);
                B = pk_fma_sv(wp[k2 + 1], x2p[k2 + 1], B);
            }
            tr[threadIdx.x * 33 + chh] = (A.x + A.y) + (B.x + B.y);
        }
        __syncthreads();
        float s = 0.f, q = 0.f;
        for (int r = 0; r < 32; ++r){
            float v = tr[(oc * 32 + r) * 33 + ch];
            s += v; q = fmaf(v, v, q);
        }
        accs[oc][ch] = s; accq[oc][ch] = q;
        __syncthreads();
        if (threadIdx.x < 32){
            int t = threadIdx.x;
            float t0 = (accs[0][t] + accs[1][t]) + (accs[2][t] + accs[3][t]);
            float t1 = (accs[4][t] + accs[5][t]) + (accs[6][t] + accs[7][t]);
            atomicAdd(&stats[128 + h2 * 32 + t], t0 + t1);
        } else if (threadIdx.x < 64){
            int t = threadIdx.x - 32;
            float t0 = (accq[0][t] + accq[1][t]) + (accq[2][t] + accq[3][t]);
            float t1 = (accq[4][t] + accq[5][t]) + (accq[6][t] + accq[7][t]);
            atomicAdd(&stats[192 + h2 * 32 + t], t0 + t1);
        }
        __syncthreads();
    }
}

// ---------------- stats3 v5: chunked x3 staging + 4-pass 32-ch transpose ----------------
__global__ __launch_bounds__(256, 4) void stats3_kernel(const float* __restrict__ xyz, const float* __restrict__ pts,
                                                        const float* __restrict__ outc, const u16* __restrict__ gidx,
                                                        const float* __restrict__ W0f, const float* __restrict__ b0f,
                                                        const float* __restrict__ W1f, const float* __restrict__ b1f,
                                                        const float* __restrict__ W2f, const float* __restrict__ b2f,
                                                        const float* __restrict__ g0, const float* __restrict__ bb0,
                                                        const float* __restrict__ g1, const float* __restrict__ bb1,
                                                        float* __restrict__ stats,
                                                        float* __restrict__ pmax, float* __restrict__ pmin){
    __shared__ float sc1[64], sh1[64], sc2[64], sh2[64];
    __shared__ float tr[256 * 33];
    __shared__ float accs[8][32], accq[8][32];
    if (threadIdx.x < 64){
        bn_coef(stats + 0,   stats + 64,  g0, bb0, threadIdx.x, sc1, sh1);
        bn_coef(stats + 128, stats + 192, g1, bb1, threadIdx.x, sc2, sh2);
    }
    __syncthreads();
    const int row = blockIdx.x * 256 + threadIdx.x;
    float x[9];
    gather_row(xyz, pts, outc, gidx, row, x);
    f32x2 x2p[32];
    #pragma unroll
    for (int j = 0; j < 64; ++j){
        float acc = b0f[j];
        #pragma unroll
        for (int k = 0; k < 9; ++k) acc = fmaf(x[k], W0f[j*9+k], acc);
        float v = fmaxf(fmaf(acc, sc1[j], sh1[j]), 0.f);
        if (j & 1) x2p[j >> 1].y = v; else x2p[j >> 1].x = v;
    }
    // phase B: x3 staged through OWN tr row in two 32-value chunks (row = 33 floats).
    // Kills x2p/x3p dual-liveness; peak = x2p(64) + x3a(32) regs.
    f32x2 x3a[16], x3b[16];
    #pragma unroll
    for (int j = 0; j < 32; ++j){
        const f32x2* wp = (const f32x2*)(W1f + j * 64);
        f32x2 A; A.x = b1f[j]; A.y = 0.f;
        f32x2 B; B.x = 0.f;    B.y = 0.f;
        #pragma unroll
        for (int k2 = 0; k2 < 32; k2 += 2){
            A = pk_fma_sv(wp[k2],     x2p[k2],     A);
            B = pk_fma_sv(wp[k2 + 1], x2p[k2 + 1], B);
        }
        tr[threadIdx.x * 33 + j] = fmaxf(fmaf((A.x + A.y) + (B.x + B.y), sc2[j], sh2[j]), 0.f);
    }
    asm volatile("" ::: "memory");   // forbid store-to-load forwarding (liveness guard)
    #pragma unroll
    for (int j = 0; j < 16; ++j){
        x3a[j].x = tr[threadIdx.x * 33 + 2*j];
        x3a[j].y = tr[threadIdx.x * 33 + 2*j + 1];
    }
    #pragma unroll
    for (int j = 32; j < 64; ++j){
        const f32x2* wp = (const f32x2*)(W1f + j * 64);
        f32x2 A; A.x = b1f[j]; A.y = 0.f;
        f32x2 B; B.x = 0.f;    B.y = 0.f;
        #pragma unroll
        for (int k2 = 0; k2 < 32; k2 += 2){
            A = pk_fma_sv(wp[k2],     x2p[k2],     A);
            B = pk_fma_sv(wp[k2 + 1], x2p[k2 + 1], B);
        }
        tr[threadIdx.x * 33 + (j - 32)] = fmaxf(fmaf((A.x + A.y) + (B.x + B.y), sc2[j], sh2[j]), 0.f);
    }
    asm volatile("" ::: "memory");
    #pragma unroll
    for (int j = 0; j < 16; ++j){
        x3b[j].x = tr[threadIdx.x * 33 + 2*j];
        x3b[j].y = tr[threadIdx.x * 33 + 2*j + 1];
    }
    const int ch = threadIdx.x & 31, oc = threadIdx.x >> 5;
    #pragma unroll
    for (int half = 0; half < 2; ++half){
        #pragma unroll
        for (int h2 = 0; h2 < 2; ++h2){
            for (int cc = 0; cc < 32; ++cc){
                int c = half * 64 + h2 * 32 + cc;
                const f32x2* wp = (const f32x2*)(W2f + c * 64);
                f32x2 A; A.x = b2f[c]; A.y = 0.f;
                f32x2 B; B.x = 0.f;    B.y = 0.f;
                #pragma unroll
                for (int k2 = 0; k2 < 16; k2 += 2){
                    A = pk_fma_sv(wp[k2],     x3a[k2],     A);
                    B = pk_fma_sv(wp[k2 + 1], x3a[k2 + 1], B);
                }
                #pragma unroll
                for (int k2 = 16; k2 < 32; k2 += 2){
                    A = pk_fma_sv(wp[k2],     x3b[k2 - 16],     A);
                    B = pk_fma_sv(wp[k2 + 1], x3b[k2 - 15],     B);
                }
                tr[threadIdx.x * 33 + cc] = (A.x + A.y) + (B.x + B.y);
            }
            __syncthreads();
            // octant oc = rows [oc*32, oc*32+32) = exactly group blockIdx*8 + oc
            float s = 0.f, q = 0.f, mx = -1e30f, mn = 1e30f;
            for (int r = 0; r < 32; ++r){
                float v = tr[(oc * 32 + r) * 33 + ch];
                s += v; q = fmaf(v, v, q);
                mx = fmaxf(mx, v); mn = fminf(mn, v);
            }
            int c = half * 64 + h2 * 32 + ch;
            int gA = blockIdx.x * 8 + oc;
            pmax[(size_t)gA * 128 + c] = mx;   // 32-lane contiguous per octant
            pmin[(size_t)gA * 128 + c] = mn;
            accs[oc][ch] = s; accq[oc][ch] = q;
            __syncthreads();
            if (threadIdx.x < 32){
                int t = threadIdx.x;
                int cc2 = half * 64 + h2 * 32 + t;
                float t0 = (accs[0][t] + accs[1][t]) + (accs[2][t] + accs[3][t]);
                float t1 = (accs[4][t] + accs[5][t]) + (accs[6][t] + accs[7][t]);
                atomicAdd(&stats[256 + cc2], t0 + t1);
            } else if (threadIdx.x < 64){
                int t = threadIdx.x - 32;
                int cc2 = half * 64 + h2 * 32 + t;
                float t0 = (accq[0][t] + accq[1][t]) + (accq[2][t] + accq[3][t]);
                float t1 = (accq[4][t] + accq[5][t]) + (accq[6][t] + accq[7][t]);
                atomicAdd(&stats[384 + cc2], t0 + t1);
            }
            __syncthreads();   // tr + accs reuse protection for next pass
        }
    }
}

// ---------------- BN3 applied to group max/min, relu, write out region 1 (f32) ----------------
__global__ __launch_bounds__(256) void pool_kernel(const float* __restrict__ stats,
                                                   const float* __restrict__ g2, const float* __restrict__ bb2,
                                                   const float* __restrict__ pmax, const float* __restrict__ pmin,
                                                   float* __restrict__ out){
    __shared__ float sc[128], sh[128];
    if (threadIdx.x < 128) bn_coef(stats + 256, stats + 384, g2, bb2, threadIdx.x, sc, sh);
    __syncthreads();
    int o = blockIdx.x * 256 + threadIdx.x;   // o = g*128 + ch, o < NGRP*128
    int ch = o & 127;
    float a = fmaf(pmax[o], sc[ch], sh[ch]);
    float b = fmaf(pmin[o], sc[ch], sh[ch]);  // affine maps interval endpoints (sc<0 covered)
    out[NGRP * 3 + o] = fmaxf(fmaxf(a, b), 0.0f);
}

extern "C" void kernel_launch(void* const* d_in, const int* in_sizes, int n_in,
                              void* d_out, int out_size, void* d_ws, size_t ws_size,
                              hipStream_t stream){
    const float* xyz = (const float*)d_in[0];
    const float* pts = (const float*)d_in[1];
    const float* W0  = (const float*)d_in[2];
    const float* b0  = (const float*)d_in[3];
    const float* g0  = (const float*)d_in[4];
    const float* bb0 = (const float*)d_in[5];
    const float* W1  = (const float*)d_in[6];
    const float* b1  = (const float*)d_in[7];
    const float* g1  = (const float*)d_in[8];
    const float* bb1 = (const float*)d_in[9];
    const float* W2  = (const float*)d_in[10];
    const float* b2  = (const float*)d_in[11];
    const float* g2  = (const float*)d_in[12];
    const float* bb2 = (const float*)d_in[13];
    float* out = (float*)d_out;   // f32 outputs: [new_xyz 49152 | new_points 2097152]

    // ws layout (bytes): stats[512f]@0 | gidx[524288 u16]@2048 |
    //                    pmax[2097152f]@1050624 | pmin@9439232 ; total 17,827,840
    if (ws_size < 17827840u) return;
    char*  ws    = (char*)d_ws;
    float* stats = (float*)ws;
    u16*   gidx  = (u16*)  (ws + 2048);
    float* pmax  = (float*)(ws + 1050624);
    float* pmin  = (float*)(ws + 9439232);

    fps_kernel  <<<16, 256, 0, stream>>>(xyz, out, stats);   // block 0 also zeroes stats
    ballq_kernel<<<NGRP/4, 256, 0, stream>>>(xyz, out, gidx);
    stats1_kernel<<<ROWS/256, 256, 0, stream>>>(xyz, pts, out, gidx, W0, b0, stats);
    stats2_kernel<<<ROWS/256, 256, 0, stream>>>(xyz, pts, out, gidx, W0, b0, W1, b1, g0, bb0, stats);
    stats3_kernel<<<ROWS/256, 256, 0, stream>>>(xyz, pts, out, gidx, W0, b0, W1, b1, W2, b2,
                                                g0, bb0, g1, bb1, stats, pmax, pmin);
    pool_kernel <<<NGRP*128/256, 256, 0, stream>>>(stats, g2, bb2, pmax, pmin, out);
}